// Round 8
// baseline (5682.849 us; speedup 1.0000x reference)
//
#include <hip/hip_runtime.h>
#include <math.h>

#define EMBD 300
#define HROW 304     // fp16 h row stride (elements) = 608 B; col300 = dinv, 301-303 = 0
#define LDF  304     // fp32 junction-phase row stride
#define KEXT 320     // extended K: 304 h(+dinv/pad) + 1 bias + 6 ee1 + 3 ee2 + 6 pad
#define BCH  160     // B cols per jt chunk (2 chunks of 160 = 320)
#define BSTR 40      // LDS B row stride (halves): 80 B
#define CE(a,b) (((a)+(b)-1)/(b))

typedef _Float16 h16;
typedef __attribute__((ext_vector_type(8))) _Float16 half8;
typedef __attribute__((ext_vector_type(4))) float f32x4;

// ---------------- utility / CSR kernels ----------------
__global__ void k_diag(float* out, int n, float v){
  int i = blockIdx.x*256 + threadIdx.x;
  if (i < n) out[i] = v;
}
__global__ void k_set_val(int* p, int n, int v){
  int i = blockIdx.x*256 + threadIdx.x;
  if (i < n) p[i] = v;
}
__global__ void k_count_src(const int* __restrict__ ei, int E, int* __restrict__ deg){
  int e = blockIdx.x*256 + threadIdx.x;
  if (e < E) atomicAdd(&deg[ei[e]], 1);
}
__global__ void k_dinv(const int* __restrict__ deg, float* __restrict__ dinv, int N){
  int i = blockIdx.x*256 + threadIdx.x;
  if (i < N) dinv[i] = 1.0f / sqrtf((float)(deg[i] + 1));   // +1 self-loop
}
__global__ void k_count_dst(const int* __restrict__ ei, int E, int* __restrict__ counts){
  int e = blockIdx.x*256 + threadIdx.x;
  if (e < E) atomicAdd(&counts[ei[E + e]], 1);
}
__global__ void k_count_ids(const int* __restrict__ ids, int n, int* __restrict__ counts){
  int i = blockIdx.x*256 + threadIdx.x;
  if (i < n) atomicAdd(&counts[ids[i]], 1);
}
__global__ void k_scan_block(const int* __restrict__ in, int M, int* __restrict__ out, int* __restrict__ bsum){
  __shared__ int s[256];
  int t = threadIdx.x, i = blockIdx.x*256 + t;
  int v = (i < M) ? in[i] : 0;
  s[t] = v; __syncthreads();
  for (int off = 1; off < 256; off <<= 1){
    int x = (t >= off) ? s[t-off] : 0;
    __syncthreads();
    s[t] += x;
    __syncthreads();
  }
  if (i < M) out[i] = s[t] - v;
  if (t == 255) bsum[blockIdx.x] = s[255];
}
__global__ void k_scan_sums(int* __restrict__ bsum, int B){   // B <= 1024
  __shared__ int s[1024];
  int t = threadIdx.x;
  int v = (t < B) ? bsum[t] : 0;
  s[t] = v; __syncthreads();
  for (int off = 1; off < 1024; off <<= 1){
    int x = (t >= off) ? s[t-off] : 0;
    __syncthreads();
    s[t] += x;
    __syncthreads();
  }
  if (t < B) bsum[t] = s[t] - v;
}
__global__ void k_scan_add(int* __restrict__ out, const int* __restrict__ bsum, int M){
  int i = blockIdx.x*256 + threadIdx.x;
  if (i < M) out[i] += bsum[blockIdx.x];
}
// entries payload: src | bt<<20 | bd<<23   (src < 2^20)
__global__ void k_fill_edges(const int* __restrict__ ei, const int* __restrict__ ea, int E, int N,
                             const int* __restrict__ offs, int* __restrict__ cur, int* __restrict__ entries){
  int e = blockIdx.x*256 + threadIdx.x;
  if (e < E){
    int s  = ei[e];
    int d  = ei[E + e];
    int bt = ea[2*e], bd = ea[2*e + 1];
    int pos = offs[d] + atomicAdd(&cur[d], 1);
    entries[pos] = s | (bt << 20) | (bd << 23);
  } else if (e < E + N){
    int i = e - E;                          // self-loop: bond type 4, dir 0
    int pos = offs[i] + atomicAdd(&cur[i], 1);
    entries[pos] = i | (4 << 20);
  }
}
__global__ void k_fill_rows(const int* __restrict__ ids, int n, const int* __restrict__ offs,
                            int* __restrict__ cur, int* __restrict__ entries){
  int i = blockIdx.x*256 + threadIdx.x;
  if (i < n){
    int g = ids[i];
    int pos = offs[g] + atomicAdd(&cur[g], 1);
    entries[pos] = i;
  }
}

// ---------------- model kernels ----------------
// h0 in "post" form: cols 0-299 = dinv[i]*(ae1+ae2)  (dinv PRE-BAKED into features),
// col300 = dinv, 301-303 = 0
__global__ void k_init_h0(const int* __restrict__ x, const float* __restrict__ ae1,
                          const float* __restrict__ ae2, const float* __restrict__ dinv,
                          h16* __restrict__ h, int N){
  int i = blockIdx.x, t = threadIdx.x;
  int a = x[2*i], b = x[2*i + 1];
  float dv = dinv[i];
  const float* e1 = ae1 + (size_t)a*EMBD;
  const float* e2 = ae2 + (size_t)b*EMBD;
  h16* hr = h + (size_t)i*HROW;
  hr[t] = (h16)(dv*(e1[t] + e2[t]));
  int c = t + 256;
  if (c < HROW){
    float v = 0.f;
    if (c < EMBD) v = dv*(e1[c] + e2[c]);
    else if (c == 300) v = dv;
    hr[c] = (h16)v;
  }
}

// extended weights (fp16): Wx[l][o][k], o,k in [0,KEXT)
// k<300: W[o][k]; k==304: b[o]; 305..310: ee1; 311..313: ee2; else 0 (incl. k=300..303)
__global__ void k_wext(const float* __restrict__ W, const float* __restrict__ b,
                       const float* __restrict__ ee1, const float* __restrict__ ee2,
                       h16* __restrict__ out){
  int l = blockIdx.y, o = blockIdx.x, t = threadIdx.x;
  h16* d = out + ((size_t)l*KEXT + o)*KEXT;
  for (int k = t; k < KEXT; k += 256){
    float v = 0.f;
    if (o < EMBD){
      if      (k < EMBD)            v = W[(size_t)l*EMBD*EMBD + (size_t)o*EMBD + k];
      else if (k == 304)            v = b[l*EMBD + o];
      else if (k >= 305 && k < 311) v = ee1[((size_t)l*6 + (k-305))*EMBD + o];
      else if (k >= 311 && k < 314) v = ee2[((size_t)l*3 + (k-311))*EMBD + o];
    }
    d[k] = (h16)v;
  }
}

__global__ void k_bn_coef(const float* __restrict__ stats, const float* __restrict__ gamma,
                          const float* __restrict__ beta, float* __restrict__ coef, float invN){
  int c = blockIdx.x*256 + threadIdx.x;
  if (c >= HROW) return;
  float sc = 0.f, sh = 0.f;
  if (c < EMBD){
    float mu  = stats[c]*invN;
    float var = stats[EMBD + c]*invN - mu*mu;
    sc = gamma[c]*rsqrtf(var + 1e-5f);
    sh = beta[c] - mu*sc;
  }
  coef[c] = sc; coef[HROW + c] = sh;
}

// streaming prepass: h := dinv[row] * relu(sc*h+sh)  (dinv PRE-BAKED);
// col300 := dinv[row]; 301-303 := 0
__global__ void __launch_bounds__(256)
k_post(h16* __restrict__ h, const float* __restrict__ coef,
       const float* __restrict__ dinv, int N){
  int idx = blockIdx.x*256 + threadIdx.x;
  int total = N * 38;                       // 38 chunks of 8 per row
  if (idx >= total) return;
  int row = idx / 38;
  int ch  = idx - row*38;
  float dv = dinv[row];
  h16* p = h + (size_t)row*HROW + ch*8;
  half8 v = *(half8*)p;
  int c0 = ch*8;
  #pragma unroll
  for (int c = 0; c < 8; c++){
    int col = c0 + c;
    float f = (float)v[c];
    float o;
    if (col < EMBD)      o = dv * fmaxf(coef[col]*f + coef[HROW + col], 0.f);
    else if (col == 300) o = dv;
    else                 o = 0.f;
    v[c] = (h16)o;
  }
  *(half8*)p = v;
}

// ---- fused layer: fragment-direct gather -> MFMA GEMM -> BN stats ----
// block = 64 dst rows; wave w owns rows w*16..+15; lane (m16,ko) owns channels
// k*32+ko*8..+8 of row m16 -> MFMA A-fragments directly in regs. Source rows are
// PRE-SCALED by dinv[src] (k_post), so aggregation is a pure packed-fp16 sum.
__global__ void __launch_bounds__(256)
k_layer(const h16* __restrict__ hPost,
        const int* __restrict__ offs, const int* __restrict__ counts,
        const int* __restrict__ entries, const h16* __restrict__ Wx,
        const float* __restrict__ dinv, h16* __restrict__ hOut,
        int N, float* __restrict__ stats)
{
  __shared__ h16  Bs[BCH][BSTR];       // 12.8 KB B chunk (160 cols x 32 k)
  __shared__ float sred[2*HROW];       //  2.4 KB BN partials
  __shared__ int   rstart[64];
  __shared__ int   rcnt[64];
  __shared__ float dvv[64];

  int tid = threadIdx.x;
  int wid = tid >> 6, lane = tid & 63;
  int m16 = lane & 15, ko = lane >> 4;
  long row0 = (long)blockIdx.x * 64;

  if (tid < 64){
    long g = row0 + tid;
    int o = 0, c = 0; float d = 0.f;
    if (g < N){ o = offs[g]; c = counts[g]; d = dinv[g]; }
    rstart[tid] = o; rcnt[tid] = c; dvv[tid] = d;
  }
  for (int i = tid; i < 2*HROW; i += 256) sred[i] = 0.f;
  __syncthreads();

  int lr = wid*16 + m16;
  int myStart = rstart[lr], myCnt = rcnt[lr];
  float di = dvv[lr];
  int cm = myCnt;
  #pragma unroll
  for (int off = 1; off < 64; off <<= 1) cm = max(cm, __shfl_xor(cm, off, 64));

  half8 acc[10];
  #pragma unroll
  for (int k = 0; k < 10; k++) acc[k] = (half8)(_Float16)0;
  float ext[8] = {0,0,0,0,0,0,0,0};
  int extbase = (ko >= 2) ? (ko - 2)*8 : 0;

  for (int j = 0; j < cm; j++){
    bool act = j < myCnt;
    int e = entries[myStart + (act ? j : 0)];
    int src = act ? (e & 0xFFFFF) : N;         // row N is all-zero
    const h16* hp = hPost + (size_t)src*HROW;
    half8 q[9];
    #pragma unroll
    for (int k = 0; k < 9; k++) q[k] = *(const half8*)(hp + k*32 + ko*8);
    half8 q9 = (half8)(_Float16)0;
    if (ko < 2) q9 = *(const half8*)(hp + 288 + ko*8);
    float wv = __shfl((float)q9[4], m16 + 16, 64);   // col300 = dinv[src] (0 if inactive)
    #pragma unroll
    for (int k = 0; k < 9; k++) acc[k] += q[k];      // rows pre-scaled by dinv[src]
    acc[9] += q9;
    unsigned msk = 1u | (1u << (1 + ((e >> 20) & 7))) | (1u << (7 + ((e >> 23) & 3)));
    #pragma unroll
    for (int c = 0; c < 8; c++)
      ext[c] += ((msk >> (extbase + c)) & 1u) ? wv : 0.f;
  }

  // scale by di; ext lanes build their k=9 fragment from the selector sums
  half8 afr[10];
  {
    _Float16 dh = (_Float16)di;
    half8 d8 = {dh,dh,dh,dh,dh,dh,dh,dh};
    #pragma unroll
    for (int k = 0; k < 10; k++) afr[k] = acc[k] * d8;
    if (ko >= 2){
      half8 x;
      #pragma unroll
      for (int c = 0; c < 8; c++) x[c] = (h16)(di * ext[c]);
      afr[9] = x;
    }
  }

  // ---- GEMM over 2 col-chunks of 160 ----
  int cr = ko * 4;
  for (int jt = 0; jt < 2; jt++){
    f32x4 a2[10];
    #pragma unroll
    for (int j = 0; j < 10; j++) a2[j] = (f32x4){0.f,0.f,0.f,0.f};
    for (int k0 = 0; k0 < 10; k0++){
      __syncthreads();
      for (int idx = tid; idx < 640; idx += 256){
        int o = idx >> 2, qd = (idx & 3) * 8;
        *(half8*)&Bs[o][qd] = *(const half8*)(Wx + (size_t)(jt*BCH + o)*KEXT + k0*32 + qd);
      }
      __syncthreads();
      #pragma unroll
      for (int j = 0; j < 10; j++){
        half8 bfr = *(const half8*)&Bs[j*16 + m16][ko*8];
        a2[j] = __builtin_amdgcn_mfma_f32_16x16x32_f16(afr[k0], bfr, a2[j], 0, 0, 0);
      }
    }
    // epilogue for these 160 cols: store + BN partials
    #pragma unroll
    for (int j = 0; j < 10; j++){
      int col = jt*BCH + j*16 + m16;
      float s = 0.f, q = 0.f;
      #pragma unroll
      for (int r = 0; r < 4; r++){
        long row = row0 + wid*16 + cr + r;
        float v = a2[j][r];
        if (col < HROW && row < N) hOut[row*HROW + col] = (h16)v;
        s += v; q += v*v;
      }
      s += __shfl_xor(s, 16, 64); s += __shfl_xor(s, 32, 64);
      q += __shfl_xor(q, 16, 64); q += __shfl_xor(q, 32, 64);
      if (ko == 0 && col < EMBD){
        atomicAdd(&sred[col], s);
        atomicAdd(&sred[HROW + col], q);
      }
    }
  }
  __syncthreads();
  for (int c = tid; c < EMBD; c += 256){
    atomicAdd(&stats[c], sred[c]);
    atomicAdd(&stats[EMBD + c], sred[HROW + c]);
  }
}

__global__ void k_pool_h(const h16* __restrict__ h, const int* __restrict__ offs,
                         const int* __restrict__ counts, const int* __restrict__ entries,
                         float* __restrict__ out, int M){
  int g = blockIdx.x, t = threadIdx.x, c1 = t + 256;
  int off = offs[g], cnt = counts[g];
  float a0 = 0.f, a1 = 0.f;
  for (int j = 0; j < cnt; j++){
    int r = entries[off + j];
    const h16* hr = h + (size_t)r*HROW;
    a0 += (float)hr[t];
    if (c1 < EMBD) a1 += (float)hr[c1];
  }
  float inv = 1.0f / fmaxf((float)cnt, 1.0f);
  float* o = out + (size_t)g*LDF;
  o[t] = a0*inv;
  if (c1 < EMBD) o[c1] = a1*inv;
}
__global__ void k_pool_f32(const float* __restrict__ h, const int* __restrict__ offs,
                           const int* __restrict__ counts, const int* __restrict__ entries,
                           float* __restrict__ out, int M){
  int g = blockIdx.x, t = threadIdx.x, c1 = t + 256;
  int off = offs[g], cnt = counts[g];
  float a0 = 0.f, a1 = 0.f;
  for (int j = 0; j < cnt; j++){
    int r = entries[off + j];
    const float* hr = h + (size_t)r*LDF;
    a0 += hr[t];
    if (c1 < EMBD) a1 += hr[c1];
  }
  float inv = 1.0f / fmaxf((float)cnt, 1.0f);
  float* o = out + (size_t)g*LDF;
  o[t] = a0*inv;
  if (c1 < EMBD) o[c1] = a1*inv;
}

// pooled rows: v = sc[c]*v + sh[c]  (last-layer BN folded past the mean-pool)
__global__ void k_affine_rows(float* __restrict__ rows, const float* __restrict__ coef, int M){
  int g = blockIdx.x, t = threadIdx.x, c1 = t + 256;
  float* r = rows + (size_t)g*LDF;
  r[t] = coef[t]*r[t] + coef[HROW + t];
  if (c1 < EMBD) r[c1] = coef[c1]*r[c1] + coef[HROW + c1];
}

__global__ void k_mask(float* __restrict__ j, const float* __restrict__ mask,
                       const float* __restrict__ memb, int M){
  int i = blockIdx.x;
  if (mask[i] <= 0.5f) return;
  int t = threadIdx.x, c1 = t + 256;
  float* jr = j + (size_t)i*LDF;
  jr[t] = memb[t];
  if (c1 < EMBD) jr[c1] = memb[c1];
}

__global__ void k_l2norm(float* __restrict__ f, int M){
  int g = blockIdx.x, t = threadIdx.x, c1 = t + 256;
  float* fr = f + (size_t)g*LDF;
  float v0 = fr[t];
  float v1 = (c1 < EMBD) ? fr[c1] : 0.f;
  float ss = v0*v0 + v1*v1;
  #pragma unroll
  for (int o = 32; o > 0; o >>= 1) ss += __shfl_down(ss, o, 64);
  __shared__ float red[4];
  int wid = t >> 6, lane = t & 63;
  if (lane == 0) red[wid] = ss;
  __syncthreads();
  if (t == 0) red[0] = 1.0f / fmaxf(sqrtf(red[0]+red[1]+red[2]+red[3]), 1e-12f);
  __syncthreads();
  float inv = red[0];
  fr[t] = v0*inv;
  if (c1 < EMBD) fr[c1] = v1*inv;
}

// fp32 GEMM for the small junction/logits matmuls
__global__ void __launch_bounds__(256)
k_gemm(const float* __restrict__ A, int lda, const float* __restrict__ W, int ldw,
       const float* __restrict__ bias, const float* __restrict__ e1, const float* __restrict__ e2,
       float* __restrict__ C, int ldc, int M, int Ncols, int K, int relu, float scale){
  __shared__ float As[16][68];
  __shared__ float Ws[16][68];
  int row0 = blockIdx.y * 64, col0 = blockIdx.x * 64;
  int tid = threadIdx.x;
  int tx = tid & 15, ty = tid >> 4;
  float acc[4][4] = {};
  for (int k0 = 0; k0 < K; k0 += 16){
    int r  = tid >> 2;
    int kk = (tid & 3) * 4;
    int gk = k0 + kk;
    float v[4] = {0.f,0.f,0.f,0.f};
    int gr = row0 + r;
    if (gr < M){
      if (gk + 3 < K){ float4 f = *(const float4*)(A + (size_t)gr*lda + gk); v[0]=f.x;v[1]=f.y;v[2]=f.z;v[3]=f.w; }
      else for (int j = 0; j < 4; j++) if (gk + j < K) v[j] = A[(size_t)gr*lda + gk + j];
    }
    As[kk+0][r]=v[0]; As[kk+1][r]=v[1]; As[kk+2][r]=v[2]; As[kk+3][r]=v[3];
    float w[4] = {0.f,0.f,0.f,0.f};
    int o = col0 + r;
    if (o < Ncols){
      if (gk + 3 < K){ float4 f = *(const float4*)(W + (size_t)o*ldw + gk); w[0]=f.x;w[1]=f.y;w[2]=f.z;w[3]=f.w; }
      else for (int j = 0; j < 4; j++) if (gk + j < K) w[j] = W[(size_t)o*ldw + gk + j];
    }
    Ws[kk+0][r]=w[0]; Ws[kk+1][r]=w[1]; Ws[kk+2][r]=w[2]; Ws[kk+3][r]=w[3];
    __syncthreads();
    #pragma unroll
    for (int k = 0; k < 16; k++){
      float4 a4 = *(const float4*)&As[k][ty*4];
      float4 b4 = *(const float4*)&Ws[k][tx*4];
      float a[4] = {a4.x,a4.y,a4.z,a4.w};
      float b[4] = {b4.x,b4.y,b4.z,b4.w};
      #pragma unroll
      for (int i = 0; i < 4; i++)
        #pragma unroll
        for (int j = 0; j < 4; j++) acc[i][j] += a[i]*b[j];
    }
    __syncthreads();
  }
  #pragma unroll
  for (int i = 0; i < 4; i++){
    int rr = row0 + ty*4 + i;
    if (rr >= M) continue;
    #pragma unroll
    for (int j = 0; j < 4; j++){
      int cc = col0 + tx*4 + j;
      if (cc >= Ncols) continue;
      float v = acc[i][j];
      if (bias) v += bias[cc];
      if (e1)   v += e1[cc];
      if (e2)   v += e2[cc];
      v *= scale;
      if (relu) v = fmaxf(v, 0.f);
      C[(size_t)rr*ldc + cc] = v;
    }
  }
}

// ---------------- host side ----------------
static inline void scan_excl(const int* counts, int M, int* offs, int* bsum, hipStream_t s){
  int B = CE(M, 256);
  k_scan_block<<<B,256,0,s>>>(counts, M, offs, bsum);
  k_scan_sums<<<1,1024,0,s>>>(bsum, B);
  k_scan_add<<<B,256,0,s>>>(offs, bsum, M);
}
static inline void gemm_f32(const float* A,int lda,const float* W,int ldw,
                            const float* bias,const float* e1,const float* e2,
                            float* C,int ldc,int M,int Ncols,int K,
                            int relu,float scale,hipStream_t s){
  dim3 grid(CE(Ncols,64), CE(M,64));
  k_gemm<<<grid,256,0,s>>>(A,lda,W,ldw,bias,e1,e2,C,ldc,M,Ncols,K,relu,scale);
}

extern "C" void kernel_launch(void* const* d_in, const int* in_sizes, int n_in,
                              void* d_out, int out_size, void* d_ws, size_t ws_size,
                              hipStream_t stream) {
  const int*   batch_x   = (const int*)d_in[0];
  const int*   batch_ei  = (const int*)d_in[1];
  const int*   batch_ea  = (const int*)d_in[2];
  const int*   batch_gid = (const int*)d_in[3];
  const int*   frag_x    = (const int*)d_in[4];
  const int*   frag_ei   = (const int*)d_in[5];
  const int*   frag_ea   = (const int*)d_in[6];
  const int*   frag_jid  = (const int*)d_in[7];
  const int*   jct_gid   = (const int*)d_in[8];
  const float* jct_mask  = (const float*)d_in[9];
  const float* ae1       = (const float*)d_in[10];
  const float* ae2       = (const float*)d_in[11];
  const float* gnn_W     = (const float*)d_in[12];
  const float* gnn_b     = (const float*)d_in[13];
  const float* gnn_ee1   = (const float*)d_in[14];
  const float* gnn_ee2   = (const float*)d_in[15];
  const float* bn_gamma  = (const float*)d_in[16];
  const float* bn_beta   = (const float*)d_in[17];
  const float* jct_W     = (const float*)d_in[18];
  const float* jct_b     = (const float*)d_in[19];
  const float* jct_ee1   = (const float*)d_in[20];
  const float* jct_ee2   = (const float*)d_in[21];
  const float* mask_emb  = (const float*)d_in[22];

  const int N = in_sizes[0] / 2;       // 200000
  const int E = in_sizes[1] / 2;       // 400000
  const int NG = 1024, NJ = 8192;

  // workspace carve-up (~252 MB)
  size_t off = 0;
  char* base = (char*)d_ws;
  auto carve = [&](size_t bytes) -> void* {
    void* p = base + off;
    off += (bytes + 255) & ~(size_t)255;
    return p;
  };
  h16*  hA      = (h16*) carve((size_t)(N+1) * HROW * 2);   // +1: zero row N
  h16*  hB      = (h16*) carve((size_t)(N+1) * HROW * 2);
  float* dinv    = (float*)carve((size_t)N * 4);
  int*   degcnt  = (int*)  carve((size_t)N * 4);
  int*   cursor  = degcnt;                       // alias: dead after k_dinv
  int*   counts  = (int*)  carve((size_t)N * 4);
  int*   offs    = (int*)  carve((size_t)(N + 1) * 4);
  int*   entries = (int*)  carve((size_t)(E + N) * 4);
  int*   bsum    = (int*)  carve(1024 * 4);
  float* stats   = (float*)carve(2 * EMBD * 4);
  float* coef    = (float*)carve(2 * HROW * 4);
  h16*  wext    = (h16*) carve((size_t)5 * KEXT * KEXT * 2);
  float* f0      = (float*)carve((size_t)NG * LDF * 4);
  float* f1      = (float*)carve((size_t)NG * LDF * 4);
  size_t required = off;
  // junction-phase fp32 buffers alias hA (dead when used)
  float* g0      = (float*)hA;
  float* t1      = (float*)((char*)hA + ((size_t)16 << 20));
  float* t2      = (float*)((char*)hA + ((size_t)32 << 20));
  (void)n_in;

  if (ws_size < required || d_ws == nullptr){
    float v = 1.0e6f + (float)(ws_size >> 20) * 1000.0f;   // encode ws MB in absmax
    k_diag<<<CE(out_size,256),256,0,stream>>>((float*)d_out, out_size, v);
    return;
  }

  // one-time prep: extended fp16 weights; zero row N of both h buffers
  { dim3 g(KEXT, 5); k_wext<<<g,256,0,stream>>>(gnn_W, gnn_b, gnn_ee1, gnn_ee2, wext); }
  hipMemsetAsync(hA + (size_t)N*HROW, 0, HROW*2, stream);
  hipMemsetAsync(hB + (size_t)N*HROW, 0, HROW*2, stream);

  const int LBLK = CE(N, 64);   // fused-layer grid

  for (int br = 0; br < 2; br++){
    const int* x  = br ? frag_x  : batch_x;
    const int* ei = br ? frag_ei : batch_ei;
    const int* ea = br ? frag_ea : batch_ea;

    // degree (by src, +1 self-loop) -> dinv
    hipMemsetAsync(degcnt, 0, (size_t)N*4, stream);
    k_count_src<<<CE(E,256),256,0,stream>>>(ei, E, degcnt);
    k_dinv<<<CE(N,256),256,0,stream>>>(degcnt, dinv, N);

    // dst-CSR over E real edges + N self-loops (layer-invariant)
    k_set_val<<<CE(N,256),256,0,stream>>>(counts, N, 1);
    k_count_dst<<<CE(E,256),256,0,stream>>>(ei, E, counts);
    scan_excl(counts, N, offs, bsum, stream);
    hipMemsetAsync(cursor, 0, (size_t)N*4, stream);
    k_fill_edges<<<CE(E+N,256),256,0,stream>>>(ei, ea, E, N, offs, cursor, entries);

    // h0 (post form) = dinv * (ae1[x0] + ae2[x1]); dinv in col 300
    k_init_h0<<<N,256,0,stream>>>(x, ae1, ae2, dinv, hA, N);

    // 5 fused layers: ping-pong; prepass (BN affine+relu+dinv pre-scale) between layers
    for (int l = 0; l < 5; l++){
      const h16* src = (l & 1) ? hB : hA;
      h16*       dst = (l & 1) ? hA : hB;
      hipMemsetAsync(stats, 0, 2*EMBD*4, stream);
      k_layer<<<LBLK,256,0,stream>>>(src, offs, counts, entries,
                                     wext + (size_t)l*KEXT*KEXT,
                                     dinv, dst, N, stats);
      k_bn_coef<<<CE(HROW,256),256,0,stream>>>(stats, bn_gamma + l*EMBD, bn_beta + l*EMBD,
                                               coef, 1.0f/(float)N);
      if (l < 4)
        k_post<<<CE(N*38,256),256,0,stream>>>(dst, coef, dinv, N);
    }
    // hB holds raw layer-4 lin output; coef holds its BN affine (no relu on last layer):
    // BN commutes with mean-pool -> apply affine on pooled rows.

    if (br == 0){
      hipMemsetAsync(counts, 0, (size_t)NG*4, stream);
      k_count_ids<<<CE(N,256),256,0,stream>>>(batch_gid, N, counts);
      scan_excl(counts, NG, offs, bsum, stream);
      hipMemsetAsync(cursor, 0, (size_t)NG*4, stream);
      k_fill_rows<<<CE(N,256),256,0,stream>>>(batch_gid, N, offs, cursor, entries);
      k_pool_h<<<NG,256,0,stream>>>(hB, offs, counts, entries, g0, NG);
      k_affine_rows<<<NG,256,0,stream>>>(g0, coef, NG);
      gemm_f32(g0, LDF, jct_W, EMBD, jct_b,
               jct_ee1 + 4*EMBD, jct_ee2,
               t1, LDF, NG, EMBD, EMBD, 1, 1.0f, stream);
      gemm_f32(t1, LDF, jct_W + EMBD*EMBD, EMBD, jct_b + EMBD,
               jct_ee1 + 6*EMBD + 4*EMBD, jct_ee2 + 3*EMBD,
               f0, LDF, NG, EMBD, EMBD, 0, 1.0f, stream);
      k_l2norm<<<NG,256,0,stream>>>(f0, NG);
    } else {
      hipMemsetAsync(counts, 0, (size_t)NJ*4, stream);
      k_count_ids<<<CE(N,256),256,0,stream>>>(frag_jid, N, counts);
      scan_excl(counts, NJ, offs, bsum, stream);
      hipMemsetAsync(cursor, 0, (size_t)NJ*4, stream);
      k_fill_rows<<<CE(N,256),256,0,stream>>>(frag_jid, N, offs, cursor, entries);
      k_pool_h<<<NJ,256,0,stream>>>(hB, offs, counts, entries, t1, NJ);
      k_affine_rows<<<NJ,256,0,stream>>>(t1, coef, NJ);
      k_mask<<<NJ,256,0,stream>>>(t1, jct_mask, mask_emb, NJ);
      gemm_f32(t1, LDF, jct_W, EMBD, jct_b,
               jct_ee1 + 4*EMBD, jct_ee2,
               t2, LDF, NJ, EMBD, EMBD, 1, 1.0f, stream);
      gemm_f32(t2, LDF, jct_W + EMBD*EMBD, EMBD, jct_b + EMBD,
               jct_ee1 + 6*EMBD + 4*EMBD, jct_ee2 + 3*EMBD,
               t1, LDF, NJ, EMBD, EMBD, 0, 1.0f, stream);
      hipMemsetAsync(counts, 0, (size_t)NG*4, stream);
      k_count_ids<<<CE(NJ,256),256,0,stream>>>(jct_gid, NJ, counts);
      scan_excl(counts, NG, offs, bsum, stream);
      hipMemsetAsync(cursor, 0, (size_t)NG*4, stream);
      k_fill_rows<<<CE(NJ,256),256,0,stream>>>(jct_gid, NJ, offs, cursor, entries);
      k_pool_f32<<<NG,256,0,stream>>>(t1, offs, counts, entries, f1, NG);
      k_l2norm<<<NG,256,0,stream>>>(f1, NG);
    }
  }

  // logits = (f0 @ f1^T) / TEMP
  gemm_f32(f0, LDF, f1, LDF, nullptr, nullptr, nullptr,
           (float*)d_out, 1024, NG, NG, EMBD, 0, 25.0f, stream);
}

// Round 9
// 4525.662 us; speedup vs baseline: 1.2557x; 1.2557x over previous
//
#include <hip/hip_runtime.h>
#include <math.h>

#define EMBD 300
#define HROW 304     // fp16 h row stride (elements) = 608 B; cols 300-303 = 0
#define LDF  304     // fp32 junction-phase row stride
#define KEXT 320     // extended K: 304 h(+pad) + 1 bias + 6 ee1 + 3 ee2 + 6 pad
#define BCH  160     // B cols per jt chunk (2 chunks of 160 = 320)
#define BSTR 40      // LDS B row stride (halves): 80 B
#define CE(a,b) (((a)+(b)-1)/(b))

typedef _Float16 h16;
typedef __attribute__((ext_vector_type(8))) _Float16 half8;
typedef __attribute__((ext_vector_type(4))) float f32x4;

// ---------------- utility / CSR kernels ----------------
__global__ void k_diag(float* out, int n, float v){
  int i = blockIdx.x*256 + threadIdx.x;
  if (i < n) out[i] = v;
}
__global__ void k_set_val(int* p, int n, int v){
  int i = blockIdx.x*256 + threadIdx.x;
  if (i < n) p[i] = v;
}
__global__ void k_count_src(const int* __restrict__ ei, int E, int* __restrict__ deg){
  int e = blockIdx.x*256 + threadIdx.x;
  if (e < E) atomicAdd(&deg[ei[e]], 1);
}
__global__ void k_dinv(const int* __restrict__ deg, float* __restrict__ dinv, int N){
  int i = blockIdx.x*256 + threadIdx.x;
  if (i < N) dinv[i] = 1.0f / sqrtf((float)(deg[i] + 1));   // +1 self-loop
}
__global__ void k_count_dst(const int* __restrict__ ei, int E, int* __restrict__ counts){
  int e = blockIdx.x*256 + threadIdx.x;
  if (e < E) atomicAdd(&counts[ei[E + e]], 1);
}
__global__ void k_count_ids(const int* __restrict__ ids, int n, int* __restrict__ counts){
  int i = blockIdx.x*256 + threadIdx.x;
  if (i < n) atomicAdd(&counts[ids[i]], 1);
}
__global__ void k_scan_block(const int* __restrict__ in, int M, int* __restrict__ out, int* __restrict__ bsum){
  __shared__ int s[256];
  int t = threadIdx.x, i = blockIdx.x*256 + t;
  int v = (i < M) ? in[i] : 0;
  s[t] = v; __syncthreads();
  for (int off = 1; off < 256; off <<= 1){
    int x = (t >= off) ? s[t-off] : 0;
    __syncthreads();
    s[t] += x;
    __syncthreads();
  }
  if (i < M) out[i] = s[t] - v;
  if (t == 255) bsum[blockIdx.x] = s[255];
}
__global__ void k_scan_sums(int* __restrict__ bsum, int B){   // B <= 1024
  __shared__ int s[1024];
  int t = threadIdx.x;
  int v = (t < B) ? bsum[t] : 0;
  s[t] = v; __syncthreads();
  for (int off = 1; off < 1024; off <<= 1){
    int x = (t >= off) ? s[t-off] : 0;
    __syncthreads();
    s[t] += x;
    __syncthreads();
  }
  if (t < B) bsum[t] = s[t] - v;
}
__global__ void k_scan_add(int* __restrict__ out, const int* __restrict__ bsum, int M){
  int i = blockIdx.x*256 + threadIdx.x;
  if (i < M) out[i] += bsum[blockIdx.x];
}
// entries payload: src | bt<<20 | bd<<23   (src < 2^20)
__global__ void k_fill_edges(const int* __restrict__ ei, const int* __restrict__ ea, int E, int N,
                             const int* __restrict__ offs, int* __restrict__ cur, int* __restrict__ entries){
  int e = blockIdx.x*256 + threadIdx.x;
  if (e < E){
    int s  = ei[e];
    int d  = ei[E + e];
    int bt = ea[2*e], bd = ea[2*e + 1];
    int pos = offs[d] + atomicAdd(&cur[d], 1);
    entries[pos] = s | (bt << 20) | (bd << 23);
  } else if (e < E + N){
    int i = e - E;                          // self-loop: bond type 4, dir 0
    int pos = offs[i] + atomicAdd(&cur[i], 1);
    entries[pos] = i | (4 << 20);
  }
}
__global__ void k_fill_rows(const int* __restrict__ ids, int n, const int* __restrict__ offs,
                            int* __restrict__ cur, int* __restrict__ entries){
  int i = blockIdx.x*256 + threadIdx.x;
  if (i < n){
    int g = ids[i];
    int pos = offs[g] + atomicAdd(&cur[g], 1);
    entries[pos] = i;
  }
}

// ---------------- model kernels ----------------
// h0: raw fp16 embeddings, cols 300-303 = 0
__global__ void k_init_h0(const int* __restrict__ x, const float* __restrict__ ae1,
                          const float* __restrict__ ae2, h16* __restrict__ h, int N){
  int i = blockIdx.x, t = threadIdx.x;
  int a = x[2*i], b = x[2*i + 1];
  const float* e1 = ae1 + (size_t)a*EMBD;
  const float* e2 = ae2 + (size_t)b*EMBD;
  h16* hr = h + (size_t)i*HROW;
  hr[t] = (h16)(e1[t] + e2[t]);
  int c = t + 256;
  if (c < HROW) hr[c] = (c < EMBD) ? (h16)(e1[c] + e2[c]) : (h16)0.f;
}

// extended weights (fp16): Wx[l][o][k], o,k in [0,KEXT)
// k<300: W[o][k]; k==304: b[o]; 305..310: ee1; 311..313: ee2; else 0
__global__ void k_wext(const float* __restrict__ W, const float* __restrict__ b,
                       const float* __restrict__ ee1, const float* __restrict__ ee2,
                       h16* __restrict__ out){
  int l = blockIdx.y, o = blockIdx.x, t = threadIdx.x;
  h16* d = out + ((size_t)l*KEXT + o)*KEXT;
  for (int k = t; k < KEXT; k += 256){
    float v = 0.f;
    if (o < EMBD){
      if      (k < EMBD)            v = W[(size_t)l*EMBD*EMBD + (size_t)o*EMBD + k];
      else if (k == 304)            v = b[l*EMBD + o];
      else if (k >= 305 && k < 311) v = ee1[((size_t)l*6 + (k-305))*EMBD + o];
      else if (k >= 311 && k < 314) v = ee2[((size_t)l*3 + (k-311))*EMBD + o];
    }
    d[k] = (h16)v;
  }
}

__global__ void k_id_coef(float* coef, h16* coefh){
  int c = blockIdx.x*256 + threadIdx.x;
  if (c < HROW){
    coef[c] = (c < EMBD) ? 1.f : 0.f;
    coef[HROW + c] = 0.f;
  }
  if (c < KEXT){
    coefh[c] = (c < EMBD) ? (h16)1.f : (h16)0.f;
    coefh[KEXT + c] = (h16)0.f;
  }
}
// BN affine from stats: fp32 (for pooled rows) + fp16 (for gather)
__global__ void k_bn_coef(const float* __restrict__ stats, const float* __restrict__ gamma,
                          const float* __restrict__ beta, float* __restrict__ coef,
                          h16* __restrict__ coefh, float invN){
  int c = blockIdx.x*256 + threadIdx.x;
  if (c >= KEXT) return;
  float sc = 0.f, sh = 0.f;
  if (c < EMBD){
    float mu  = stats[c]*invN;
    float var = stats[EMBD + c]*invN - mu*mu;
    sc = gamma[c]*rsqrtf(var + 1e-5f);
    sh = beta[c] - mu*sc;
  }
  if (c < HROW){ coef[c] = sc; coef[HROW + c] = sh; }
  coefh[c] = (h16)sc; coefh[KEXT + c] = (h16)sh;
}

// ---- fused layer: fixed-8 fan-out gather (affine+relu in-flight) -> MFMA -> BN stats ----
// block = 64 dst rows; wave w owns rows w*16..+15; lane (m16,ko) owns channels
// {k*32+ko*8..+8} of row m16. hRaw = previous layer's RAW lin output (or h0).
template<int RELU>
__global__ void __launch_bounds__(256)
k_layer(const h16* __restrict__ hRaw, const h16* __restrict__ coefh,
        const float* __restrict__ dinv,
        const int* __restrict__ offs, const int* __restrict__ counts,
        const int* __restrict__ entries, const h16* __restrict__ Wx,
        h16* __restrict__ hOut, int N, float* __restrict__ stats)
{
  __shared__ h16  Bs[BCH][BSTR];       // 12.8 KB B chunk
  __shared__ float sred[2*HROW];       //  2.4 KB BN partials
  __shared__ int   rstart[64];
  __shared__ int   rcnt[64];
  __shared__ float dvv[64];

  int tid = threadIdx.x;
  int wid = tid >> 6, lane = tid & 63;
  int m16 = lane & 15, ko = lane >> 4;
  long row0 = (long)blockIdx.x * 64;

  if (tid < 64){
    long g = row0 + tid;
    int o = 0, c = 0; float d = 0.f;
    if (g < N){ o = offs[g]; c = counts[g]; d = dinv[g]; }
    rstart[tid] = o; rcnt[tid] = c; dvv[tid] = d;
  }
  for (int i = tid; i < 2*HROW; i += 256) sred[i] = 0.f;
  __syncthreads();

  int lr = wid*16 + m16;
  int myStart = rstart[lr], myCnt = rcnt[lr];
  float di = dvv[lr];

  // ---- prefetch up to 8 edge descriptors + weights ----
  int srcA[8]; float wvA[8]; int eA[8];
  #pragma unroll
  for (int j = 0; j < 8; j++){
    int e = entries[myStart + j];               // bounded over-read ok (within ws)
    bool act = j < myCnt;
    int s = act ? (e & 0xFFFFF) : N;            // row N is all-zero
    float wv = dinv[act ? s : 0];
    wvA[j] = act ? wv : 0.f;
    srcA[j] = s; eA[j] = e;
  }
  float ext[8] = {0,0,0,0,0,0,0,0};
  if (ko >= 2){
    int extbase = (ko - 2)*8;
    #pragma unroll
    for (int j = 0; j < 8; j++){
      unsigned msk = 1u | (1u << (1 + ((eA[j] >> 20) & 7))) | (1u << (7 + ((eA[j] >> 23) & 3)));
      #pragma unroll
      for (int c = 0; c < 8; c++)
        ext[c] += ((msk >> (extbase + c)) & 1u) ? wvA[j] : 0.f;
    }
  }
  half8 wvh[8];
  #pragma unroll
  for (int j = 0; j < 8; j++){
    _Float16 w = (_Float16)wvA[j];
    #pragma unroll
    for (int c = 0; c < 8; c++) wvh[j][c] = w;
  }

  half8 acc[10];
  #pragma unroll
  for (int k = 0; k < 10; k++) acc[k] = (half8)(_Float16)0;

  // ---- rare overflow: rows with cnt > 8 (per-lane divergent) ----
  if (__any(myCnt > 8)){
    for (int j = 8; j < myCnt; j++){
      int e = entries[myStart + j];
      int s = e & 0xFFFFF;
      float wv = dinv[s];
      if (ko >= 2){
        int extbase = (ko - 2)*8;
        unsigned msk = 1u | (1u << (1 + ((e >> 20) & 7))) | (1u << (7 + ((e >> 23) & 3)));
        #pragma unroll
        for (int c = 0; c < 8; c++)
          ext[c] += ((msk >> (extbase + c)) & 1u) ? wv : 0.f;
      }
      _Float16 wh = (_Float16)wv;
      half8 w8; 
      #pragma unroll
      for (int c = 0; c < 8; c++) w8[c] = wh;
      #pragma unroll
      for (int k = 0; k < 10; k++){
        if (k == 9 && ko >= 2) break;
        half8 sck = *(const half8*)&coefh[k*32 + ko*8];
        half8 shk = *(const half8*)&coefh[KEXT + k*32 + ko*8];
        half8 x = *(const half8*)(hRaw + (size_t)s*HROW + k*32 + ko*8);
        half8 y = sck*x + shk;
        if (RELU){
          #pragma unroll
          for (int c = 0; c < 8; c++) y[c] = y[c] > (_Float16)0 ? y[c] : (_Float16)0;
        }
        acc[k] += w8*y;
      }
    }
  }

  // ---- main gather: chunk-outer, fixed 8 edges inner (8 loads in flight) ----
  #pragma unroll
  for (int k = 0; k < 9; k++){
    half8 sck = *(const half8*)&coefh[k*32 + ko*8];
    half8 shk = *(const half8*)&coefh[KEXT + k*32 + ko*8];
    half8 a = acc[k];
    #pragma unroll
    for (int j = 0; j < 8; j++){
      half8 x = *(const half8*)(hRaw + (size_t)srcA[j]*HROW + k*32 + ko*8);
      half8 y = sck*x + shk;
      if (RELU){
        #pragma unroll
        for (int c = 0; c < 8; c++) y[c] = y[c] > (_Float16)0 ? y[c] : (_Float16)0;
      }
      a += wvh[j]*y;
    }
    acc[k] = a;
  }
  { // k = 9: ko<2 covers cols 288-303 (coef 300-303 = 0); ko>=2 = ext scalars
    half8 a = acc[9];
    if (ko < 2){
      half8 sck = *(const half8*)&coefh[288 + ko*8];
      half8 shk = *(const half8*)&coefh[KEXT + 288 + ko*8];
      #pragma unroll
      for (int j = 0; j < 8; j++){
        half8 x = *(const half8*)(hRaw + (size_t)srcA[j]*HROW + 288 + ko*8);
        half8 y = sck*x + shk;
        if (RELU){
          #pragma unroll
          for (int c = 0; c < 8; c++) y[c] = y[c] > (_Float16)0 ? y[c] : (_Float16)0;
        }
        a += wvh[j]*y;
      }
    } else {
      #pragma unroll
      for (int c = 0; c < 8; c++) a[c] += (_Float16)ext[c];
    }
    acc[9] = a;
  }

  // scale by dinv[dst]
  half8 afr[10];
  {
    _Float16 dh = (_Float16)di;
    half8 d8;
    #pragma unroll
    for (int c = 0; c < 8; c++) d8[c] = dh;
    #pragma unroll
    for (int k = 0; k < 10; k++) afr[k] = acc[k] * d8;
  }

  // ---- GEMM over 2 col-chunks of 160 ----
  int cr = ko * 4;
  for (int jt = 0; jt < 2; jt++){
    f32x4 a2[10];
    #pragma unroll
    for (int j = 0; j < 10; j++) a2[j] = (f32x4){0.f,0.f,0.f,0.f};
    for (int k0 = 0; k0 < 10; k0++){
      __syncthreads();
      for (int idx = tid; idx < 640; idx += 256){
        int o = idx >> 2, qd = (idx & 3) * 8;
        *(half8*)&Bs[o][qd] = *(const half8*)(Wx + (size_t)(jt*BCH + o)*KEXT + k0*32 + qd);
      }
      __syncthreads();
      #pragma unroll
      for (int j = 0; j < 10; j++){
        half8 bfr = *(const half8*)&Bs[j*16 + m16][ko*8];
        a2[j] = __builtin_amdgcn_mfma_f32_16x16x32_f16(afr[k0], bfr, a2[j], 0, 0, 0);
      }
    }
    // epilogue: store raw lin + BN partials
    #pragma unroll
    for (int j = 0; j < 10; j++){
      int col = jt*BCH + j*16 + m16;
      float s = 0.f, q = 0.f;
      #pragma unroll
      for (int r = 0; r < 4; r++){
        long row = row0 + wid*16 + cr + r;
        float v = a2[j][r];
        if (col < HROW && row < N) hOut[row*HROW + col] = (h16)v;
        s += v; q += v*v;
      }
      s += __shfl_xor(s, 16, 64); s += __shfl_xor(s, 32, 64);
      q += __shfl_xor(q, 16, 64); q += __shfl_xor(q, 32, 64);
      if (ko == 0 && col < EMBD){
        atomicAdd(&sred[col], s);
        atomicAdd(&sred[HROW + col], q);
      }
    }
  }
  __syncthreads();
  for (int c = tid; c < EMBD; c += 256){
    atomicAdd(&stats[c], sred[c]);
    atomicAdd(&stats[EMBD + c], sred[HROW + c]);
  }
}

__global__ void k_pool_h(const h16* __restrict__ h, const int* __restrict__ offs,
                         const int* __restrict__ counts, const int* __restrict__ entries,
                         float* __restrict__ out, int M){
  int g = blockIdx.x, t = threadIdx.x, c1 = t + 256;
  int off = offs[g], cnt = counts[g];
  float a0 = 0.f, a1 = 0.f;
  for (int j = 0; j < cnt; j++){
    int r = entries[off + j];
    const h16* hr = h + (size_t)r*HROW;
    a0 += (float)hr[t];
    if (c1 < EMBD) a1 += (float)hr[c1];
  }
  float inv = 1.0f / fmaxf((float)cnt, 1.0f);
  float* o = out + (size_t)g*LDF;
  o[t] = a0*inv;
  if (c1 < EMBD) o[c1] = a1*inv;
}
__global__ void k_pool_f32(const float* __restrict__ h, const int* __restrict__ offs,
                           const int* __restrict__ counts, const int* __restrict__ entries,
                           float* __restrict__ out, int M){
  int g = blockIdx.x, t = threadIdx.x, c1 = t + 256;
  int off = offs[g], cnt = counts[g];
  float a0 = 0.f, a1 = 0.f;
  for (int j = 0; j < cnt; j++){
    int r = entries[off + j];
    const float* hr = h + (size_t)r*LDF;
    a0 += hr[t];
    if (c1 < EMBD) a1 += hr[c1];
  }
  float inv = 1.0f / fmaxf((float)cnt, 1.0f);
  float* o = out + (size_t)g*LDF;
  o[t] = a0*inv;
  if (c1 < EMBD) o[c1] = a1*inv;
}

// pooled rows: v = sc[c]*v + sh[c]  (last-layer BN folded past the mean-pool)
__global__ void k_affine_rows(float* __restrict__ rows, const float* __restrict__ coef, int M){
  int g = blockIdx.x, t = threadIdx.x, c1 = t + 256;
  float* r = rows + (size_t)g*LDF;
  r[t] = coef[t]*r[t] + coef[HROW + t];
  if (c1 < EMBD) r[c1] = coef[c1]*r[c1] + coef[HROW + c1];
}

__global__ void k_mask(float* __restrict__ j, const float* __restrict__ mask,
                       const float* __restrict__ memb, int M){
  int i = blockIdx.x;
  if (mask[i] <= 0.5f) return;
  int t = threadIdx.x, c1 = t + 256;
  float* jr = j + (size_t)i*LDF;
  jr[t] = memb[t];
  if (c1 < EMBD) jr[c1] = memb[c1];
}

__global__ void k_l2norm(float* __restrict__ f, int M){
  int g = blockIdx.x, t = threadIdx.x, c1 = t + 256;
  float* fr = f + (size_t)g*LDF;
  float v0 = fr[t];
  float v1 = (c1 < EMBD) ? fr[c1] : 0.f;
  float ss = v0*v0 + v1*v1;
  #pragma unroll
  for (int o = 32; o > 0; o >>= 1) ss += __shfl_down(ss, o, 64);
  __shared__ float red[4];
  int wid = t >> 6, lane = t & 63;
  if (lane == 0) red[wid] = ss;
  __syncthreads();
  if (t == 0) red[0] = 1.0f / fmaxf(sqrtf(red[0]+red[1]+red[2]+red[3]), 1e-12f);
  __syncthreads();
  float inv = red[0];
  fr[t] = v0*inv;
  if (c1 < EMBD) fr[c1] = v1*inv;
}

// fp32 GEMM for the small junction/logits matmuls
__global__ void __launch_bounds__(256)
k_gemm(const float* __restrict__ A, int lda, const float* __restrict__ W, int ldw,
       const float* __restrict__ bias, const float* __restrict__ e1, const float* __restrict__ e2,
       float* __restrict__ C, int ldc, int M, int Ncols, int K, int relu, float scale){
  __shared__ float As[16][68];
  __shared__ float Ws[16][68];
  int row0 = blockIdx.y * 64, col0 = blockIdx.x * 64;
  int tid = threadIdx.x;
  int tx = tid & 15, ty = tid >> 4;
  float acc[4][4] = {};
  for (int k0 = 0; k0 < K; k0 += 16){
    int r  = tid >> 2;
    int kk = (tid & 3) * 4;
    int gk = k0 + kk;
    float v[4] = {0.f,0.f,0.f,0.f};
    int gr = row0 + r;
    if (gr < M){
      if (gk + 3 < K){ float4 f = *(const float4*)(A + (size_t)gr*lda + gk); v[0]=f.x;v[1]=f.y;v[2]=f.z;v[3]=f.w; }
      else for (int j = 0; j < 4; j++) if (gk + j < K) v[j] = A[(size_t)gr*lda + gk + j];
    }
    As[kk+0][r]=v[0]; As[kk+1][r]=v[1]; As[kk+2][r]=v[2]; As[kk+3][r]=v[3];
    float w[4] = {0.f,0.f,0.f,0.f};
    int o = col0 + r;
    if (o < Ncols){
      if (gk + 3 < K){ float4 f = *(const float4*)(W + (size_t)o*ldw + gk); w[0]=f.x;w[1]=f.y;w[2]=f.z;w[3]=f.w; }
      else for (int j = 0; j < 4; j++) if (gk + j < K) w[j] = W[(size_t)o*ldw + gk + j];
    }
    Ws[kk+0][r]=w[0]; Ws[kk+1][r]=w[1]; Ws[kk+2][r]=w[2]; Ws[kk+3][r]=w[3];
    __syncthreads();
    #pragma unroll
    for (int k = 0; k < 16; k++){
      float4 a4 = *(const float4*)&As[k][ty*4];
      float4 b4 = *(const float4*)&Ws[k][tx*4];
      float a[4] = {a4.x,a4.y,a4.z,a4.w};
      float b[4] = {b4.x,b4.y,b4.z,b4.w};
      #pragma unroll
      for (int i = 0; i < 4; i++)
        #pragma unroll
        for (int j = 0; j < 4; j++) acc[i][j] += a[i]*b[j];
    }
    __syncthreads();
  }
  #pragma unroll
  for (int i = 0; i < 4; i++){
    int rr = row0 + ty*4 + i;
    if (rr >= M) continue;
    #pragma unroll
    for (int j = 0; j < 4; j++){
      int cc = col0 + tx*4 + j;
      if (cc >= Ncols) continue;
      float v = acc[i][j];
      if (bias) v += bias[cc];
      if (e1)   v += e1[cc];
      if (e2)   v += e2[cc];
      v *= scale;
      if (relu) v = fmaxf(v, 0.f);
      C[(size_t)rr*ldc + cc] = v;
    }
  }
}

// ---------------- host side ----------------
static inline void scan_excl(const int* counts, int M, int* offs, int* bsum, hipStream_t s){
  int B = CE(M, 256);
  k_scan_block<<<B,256,0,s>>>(counts, M, offs, bsum);
  k_scan_sums<<<1,1024,0,s>>>(bsum, B);
  k_scan_add<<<B,256,0,s>>>(offs, bsum, M);
}
static inline void gemm_f32(const float* A,int lda,const float* W,int ldw,
                            const float* bias,const float* e1,const float* e2,
                            float* C,int ldc,int M,int Ncols,int K,
                            int relu,float scale,hipStream_t s){
  dim3 grid(CE(Ncols,64), CE(M,64));
  k_gemm<<<grid,256,0,s>>>(A,lda,W,ldw,bias,e1,e2,C,ldc,M,Ncols,K,relu,scale);
}

extern "C" void kernel_launch(void* const* d_in, const int* in_sizes, int n_in,
                              void* d_out, int out_size, void* d_ws, size_t ws_size,
                              hipStream_t stream) {
  const int*   batch_x   = (const int*)d_in[0];
  const int*   batch_ei  = (const int*)d_in[1];
  const int*   batch_ea  = (const int*)d_in[2];
  const int*   batch_gid = (const int*)d_in[3];
  const int*   frag_x    = (const int*)d_in[4];
  const int*   frag_ei   = (const int*)d_in[5];
  const int*   frag_ea   = (const int*)d_in[6];
  const int*   frag_jid  = (const int*)d_in[7];
  const int*   jct_gid   = (const int*)d_in[8];
  const float* jct_mask  = (const float*)d_in[9];
  const float* ae1       = (const float*)d_in[10];
  const float* ae2       = (const float*)d_in[11];
  const float* gnn_W     = (const float*)d_in[12];
  const float* gnn_b     = (const float*)d_in[13];
  const float* gnn_ee1   = (const float*)d_in[14];
  const float* gnn_ee2   = (const float*)d_in[15];
  const float* bn_gamma  = (const float*)d_in[16];
  const float* bn_beta   = (const float*)d_in[17];
  const float* jct_W     = (const float*)d_in[18];
  const float* jct_b     = (const float*)d_in[19];
  const float* jct_ee1   = (const float*)d_in[20];
  const float* jct_ee2   = (const float*)d_in[21];
  const float* mask_emb  = (const float*)d_in[22];

  const int N = in_sizes[0] / 2;       // 200000
  const int E = in_sizes[1] / 2;       // 400000
  const int NG = 1024, NJ = 8192;

  // workspace carve-up (~252 MB)
  size_t off = 0;
  char* base = (char*)d_ws;
  auto carve = [&](size_t bytes) -> void* {
    void* p = base + off;
    off += (bytes + 255) & ~(size_t)255;
    return p;
  };
  h16*  hA      = (h16*) carve((size_t)(N+1) * HROW * 2);   // +1: zero row N
  h16*  hB      = (h16*) carve((size_t)(N+1) * HROW * 2);
  float* dinv    = (float*)carve((size_t)N * 4);
  int*   degcnt  = (int*)  carve((size_t)N * 4);
  int*   cursor  = degcnt;                       // alias: dead after k_dinv
  int*   counts  = (int*)  carve((size_t)N * 4);
  int*   offs    = (int*)  carve((size_t)(N + 1) * 4);
  int*   entries = (int*)  carve((size_t)(E + N) * 4);
  int*   bsum    = (int*)  carve(1024 * 4);
  float* stats   = (float*)carve(2 * EMBD * 4);
  float* coef    = (float*)carve(2 * HROW * 4);
  float* idcoef  = (float*)carve(2 * HROW * 4);
  h16*  coefh   = (h16*) carve(2 * KEXT * 2);
  h16*  idcoefh = (h16*) carve(2 * KEXT * 2);
  h16*  wext    = (h16*) carve((size_t)5 * KEXT * KEXT * 2);
  float* f0      = (float*)carve((size_t)NG * LDF * 4);
  float* f1      = (float*)carve((size_t)NG * LDF * 4);
  size_t required = off;
  // junction-phase fp32 buffers alias hA (dead when used)
  float* g0      = (float*)hA;
  float* t1      = (float*)((char*)hA + ((size_t)16 << 20));
  float* t2      = (float*)((char*)hA + ((size_t)32 << 20));
  (void)n_in;

  if (ws_size < required || d_ws == nullptr){
    float v = 1.0e6f + (float)(ws_size >> 20) * 1000.0f;   // encode ws MB in absmax
    k_diag<<<CE(out_size,256),256,0,stream>>>((float*)d_out, out_size, v);
    return;
  }

  // one-time prep: extended fp16 weights; identity coef; zero row N of both h buffers
  { dim3 g(KEXT, 5); k_wext<<<g,256,0,stream>>>(gnn_W, gnn_b, gnn_ee1, gnn_ee2, wext); }
  k_id_coef<<<CE(KEXT,256),256,0,stream>>>(idcoef, idcoefh);
  hipMemsetAsync(hA + (size_t)N*HROW, 0, HROW*2, stream);
  hipMemsetAsync(hB + (size_t)N*HROW, 0, HROW*2, stream);

  const int LBLK = CE(N, 64);   // fused-layer grid

  for (int br = 0; br < 2; br++){
    const int* x  = br ? frag_x  : batch_x;
    const int* ei = br ? frag_ei : batch_ei;
    const int* ea = br ? frag_ea : batch_ea;

    // degree (by src, +1 self-loop) -> dinv
    hipMemsetAsync(degcnt, 0, (size_t)N*4, stream);
    k_count_src<<<CE(E,256),256,0,stream>>>(ei, E, degcnt);
    k_dinv<<<CE(N,256),256,0,stream>>>(degcnt, dinv, N);

    // dst-CSR over E real edges + N self-loops (layer-invariant)
    k_set_val<<<CE(N,256),256,0,stream>>>(counts, N, 1);
    k_count_dst<<<CE(E,256),256,0,stream>>>(ei, E, counts);
    scan_excl(counts, N, offs, bsum, stream);
    hipMemsetAsync(cursor, 0, (size_t)N*4, stream);
    k_fill_edges<<<CE(E+N,256),256,0,stream>>>(ei, ea, E, N, offs, cursor, entries);

    // h0 raw = ae1[x0] + ae2[x1]
    k_init_h0<<<N,256,0,stream>>>(x, ae1, ae2, hA, N);

    // 5 fused layers, ping-pong; BN affine+relu applied in the NEXT layer's gather
    for (int l = 0; l < 5; l++){
      const h16* src = (l & 1) ? hB : hA;
      h16*       dst = (l & 1) ? hA : hB;
      const h16* ch  = (l == 0) ? idcoefh : coefh;
      hipMemsetAsync(stats, 0, 2*EMBD*4, stream);
      if (l == 0)
        k_layer<0><<<LBLK,256,0,stream>>>(src, ch, dinv, offs, counts, entries,
                                          wext + (size_t)l*KEXT*KEXT, dst, N, stats);
      else
        k_layer<1><<<LBLK,256,0,stream>>>(src, ch, dinv, offs, counts, entries,
                                          wext + (size_t)l*KEXT*KEXT, dst, N, stats);
      k_bn_coef<<<CE(KEXT,256),256,0,stream>>>(stats, bn_gamma + l*EMBD, bn_beta + l*EMBD,
                                               coef, coefh, 1.0f/(float)N);
    }
    // hB holds raw layer-4 lin output; coef holds its BN affine (no relu on last layer):
    // BN commutes with mean-pool -> apply affine on pooled rows.

    if (br == 0){
      hipMemsetAsync(counts, 0, (size_t)NG*4, stream);
      k_count_ids<<<CE(N,256),256,0,stream>>>(batch_gid, N, counts);
      scan_excl(counts, NG, offs, bsum, stream);
      hipMemsetAsync(cursor, 0, (size_t)NG*4, stream);
      k_fill_rows<<<CE(N,256),256,0,stream>>>(batch_gid, N, offs, cursor, entries);
      k_pool_h<<<NG,256,0,stream>>>(hB, offs, counts, entries, g0, NG);
      k_affine_rows<<<NG,256,0,stream>>>(g0, coef, NG);
      gemm_f32(g0, LDF, jct_W, EMBD, jct_b,
               jct_ee1 + 4*EMBD, jct_ee2,
               t1, LDF, NG, EMBD, EMBD, 1, 1.0f, stream);
      gemm_f32(t1, LDF, jct_W + EMBD*EMBD, EMBD, jct_b + EMBD,
               jct_ee1 + 6*EMBD + 4*EMBD, jct_ee2 + 3*EMBD,
               f0, LDF, NG, EMBD, EMBD, 0, 1.0f, stream);
      k_l2norm<<<NG,256,0,stream>>>(f0, NG);
    } else {
      hipMemsetAsync(counts, 0, (size_t)NJ*4, stream);
      k_count_ids<<<CE(N,256),256,0,stream>>>(frag_jid, N, counts);
      scan_excl(counts, NJ, offs, bsum, stream);
      hipMemsetAsync(cursor, 0, (size_t)NJ*4, stream);
      k_fill_rows<<<CE(N,256),256,0,stream>>>(frag_jid, N, offs, cursor, entries);
      k_pool_h<<<NJ,256,0,stream>>>(hB, offs, counts, entries, t1, NJ);
      k_affine_rows<<<NJ,256,0,stream>>>(t1, coef, NJ);
      k_mask<<<NJ,256,0,stream>>>(t1, jct_mask, mask_emb, NJ);
      gemm_f32(t1, LDF, jct_W, EMBD, jct_b,
               jct_ee1 + 4*EMBD, jct_ee2,
               t2, LDF, NJ, EMBD, EMBD, 1, 1.0f, stream);
      gemm_f32(t2, LDF, jct_W + EMBD*EMBD, EMBD, jct_b + EMBD,
               jct_ee1 + 6*EMBD + 4*EMBD, jct_ee2 + 3*EMBD,
               t1, LDF, NJ, EMBD, EMBD, 0, 1.0f, stream);
      hipMemsetAsync(counts, 0, (size_t)NG*4, stream);
      k_count_ids<<<CE(NJ,256),256,0,stream>>>(jct_gid, NJ, counts);
      scan_excl(counts, NG, offs, bsum, stream);
      hipMemsetAsync(cursor, 0, (size_t)NG*4, stream);
      k_fill_rows<<<CE(NJ,256),256,0,stream>>>(jct_gid, NJ, offs, cursor, entries);
      k_pool_f32<<<NG,256,0,stream>>>(t1, offs, counts, entries, f1, NG);
      k_l2norm<<<NG,256,0,stream>>>(f1, NG);
    }
  }

  // logits = (f0 @ f1^T) / TEMP
  gemm_f32(f0, LDF, f1, LDF, nullptr, nullptr, nullptr,
           (float*)d_out, 1024, NG, NG, EMBD, 0, 25.0f, stream);
}

// Round 10
// 4289.479 us; speedup vs baseline: 1.3248x; 1.0551x over previous
//
#include <hip/hip_runtime.h>
#include <math.h>

#define EMBD 300
#define HROW 304     // fp16 h row stride (elements) = 608 B; cols 300-303 = 0
#define LDF  304     // fp32 junction-phase row stride
#define KEXT 320     // extended K: 304 h(+pad) + 1 bias + 6 ee1 + 3 ee2 + 6 pad
#define BCH  160     // B cols per jt chunk (2 chunks of 160 = 320)
#define BSTR 40      // LDS B row stride (halves): 80 B
#define TS   168     // LDS C-tile row stride (halves): 336 B, 16B-aligned
#define CE(a,b) (((a)+(b)-1)/(b))

typedef _Float16 h16;
typedef __attribute__((ext_vector_type(8))) _Float16 half8;
typedef __attribute__((ext_vector_type(4))) float f32x4;

// ---------------- utility / CSR kernels ----------------
__global__ void k_diag(float* out, int n, float v){
  int i = blockIdx.x*256 + threadIdx.x;
  if (i < n) out[i] = v;
}
__global__ void k_set_val(int* p, int n, int v){
  int i = blockIdx.x*256 + threadIdx.x;
  if (i < n) p[i] = v;
}
__global__ void k_count_src(const int* __restrict__ ei, int E, int* __restrict__ deg){
  int e = blockIdx.x*256 + threadIdx.x;
  if (e < E) atomicAdd(&deg[ei[e]], 1);
}
__global__ void k_dinv(const int* __restrict__ deg, float* __restrict__ dinv, int N){
  int i = blockIdx.x*256 + threadIdx.x;
  if (i < N) dinv[i] = 1.0f / sqrtf((float)(deg[i] + 1));   // +1 self-loop
}
__global__ void k_count_dst(const int* __restrict__ ei, int E, int* __restrict__ counts){
  int e = blockIdx.x*256 + threadIdx.x;
  if (e < E) atomicAdd(&counts[ei[E + e]], 1);
}
__global__ void k_count_ids(const int* __restrict__ ids, int n, int* __restrict__ counts){
  int i = blockIdx.x*256 + threadIdx.x;
  if (i < n) atomicAdd(&counts[ids[i]], 1);
}
__global__ void k_scan_block(const int* __restrict__ in, int M, int* __restrict__ out, int* __restrict__ bsum){
  __shared__ int s[256];
  int t = threadIdx.x, i = blockIdx.x*256 + t;
  int v = (i < M) ? in[i] : 0;
  s[t] = v; __syncthreads();
  for (int off = 1; off < 256; off <<= 1){
    int x = (t >= off) ? s[t-off] : 0;
    __syncthreads();
    s[t] += x;
    __syncthreads();
  }
  if (i < M) out[i] = s[t] - v;
  if (t == 255) bsum[blockIdx.x] = s[255];
}
__global__ void k_scan_sums(int* __restrict__ bsum, int B){   // B <= 1024
  __shared__ int s[1024];
  int t = threadIdx.x;
  int v = (t < B) ? bsum[t] : 0;
  s[t] = v; __syncthreads();
  for (int off = 1; off < 1024; off <<= 1){
    int x = (t >= off) ? s[t-off] : 0;
    __syncthreads();
    s[t] += x;
    __syncthreads();
  }
  if (t < B) bsum[t] = s[t] - v;
}
__global__ void k_scan_add(int* __restrict__ out, const int* __restrict__ bsum, int M){
  int i = blockIdx.x*256 + threadIdx.x;
  if (i < M) out[i] += bsum[blockIdx.x];
}
// entries payload: src | bt<<20 | bd<<23   (src < 2^20)
__global__ void k_fill_edges(const int* __restrict__ ei, const int* __restrict__ ea, int E, int N,
                             const int* __restrict__ offs, int* __restrict__ cur, int* __restrict__ entries){
  int e = blockIdx.x*256 + threadIdx.x;
  if (e < E){
    int s  = ei[e];
    int d  = ei[E + e];
    int bt = ea[2*e], bd = ea[2*e + 1];
    int pos = offs[d] + atomicAdd(&cur[d], 1);
    entries[pos] = s | (bt << 20) | (bd << 23);
  } else if (e < E + N){
    int i = e - E;                          // self-loop: bond type 4, dir 0
    int pos = offs[i] + atomicAdd(&cur[i], 1);
    entries[pos] = i | (4 << 20);
  }
}
__global__ void k_fill_rows(const int* __restrict__ ids, int n, const int* __restrict__ offs,
                            int* __restrict__ cur, int* __restrict__ entries){
  int i = blockIdx.x*256 + threadIdx.x;
  if (i < n){
    int g = ids[i];
    int pos = offs[g] + atomicAdd(&cur[g], 1);
    entries[pos] = i;
  }
}

// ---------------- model kernels ----------------
// h0: raw fp16 embeddings, cols 300-303 = 0
__global__ void k_init_h0(const int* __restrict__ x, const float* __restrict__ ae1,
                          const float* __restrict__ ae2, h16* __restrict__ h, int N){
  int i = blockIdx.x, t = threadIdx.x;
  int a = x[2*i], b = x[2*i + 1];
  const float* e1 = ae1 + (size_t)a*EMBD;
  const float* e2 = ae2 + (size_t)b*EMBD;
  h16* hr = h + (size_t)i*HROW;
  hr[t] = (h16)(e1[t] + e2[t]);
  int c = t + 256;
  if (c < HROW) hr[c] = (c < EMBD) ? (h16)(e1[c] + e2[c]) : (h16)0.f;
}

// extended weights (fp16): Wx[l][o][k], o,k in [0,KEXT)
// k<300: W[o][k]; k==304: b[o]; 305..310: ee1; 311..313: ee2; else 0
__global__ void k_wext(const float* __restrict__ W, const float* __restrict__ b,
                       const float* __restrict__ ee1, const float* __restrict__ ee2,
                       h16* __restrict__ out){
  int l = blockIdx.y, o = blockIdx.x, t = threadIdx.x;
  h16* d = out + ((size_t)l*KEXT + o)*KEXT;
  for (int k = t; k < KEXT; k += 256){
    float v = 0.f;
    if (o < EMBD){
      if      (k < EMBD)            v = W[(size_t)l*EMBD*EMBD + (size_t)o*EMBD + k];
      else if (k == 304)            v = b[l*EMBD + o];
      else if (k >= 305 && k < 311) v = ee1[((size_t)l*6 + (k-305))*EMBD + o];
      else if (k >= 311 && k < 314) v = ee2[((size_t)l*3 + (k-311))*EMBD + o];
    }
    d[k] = (h16)v;
  }
}

__global__ void k_id_coef(float* coef, h16* coefh){
  int c = blockIdx.x*256 + threadIdx.x;
  if (c < HROW){
    coef[c] = (c < EMBD) ? 1.f : 0.f;
    coef[HROW + c] = 0.f;
  }
  if (c < KEXT){
    coefh[c] = (c < EMBD) ? (h16)1.f : (h16)0.f;
    coefh[KEXT + c] = (h16)0.f;
  }
}
// BN affine from stats: fp32 (for pooled rows) + fp16 (for gather)
__global__ void k_bn_coef(const float* __restrict__ stats, const float* __restrict__ gamma,
                          const float* __restrict__ beta, float* __restrict__ coef,
                          h16* __restrict__ coefh, float invN){
  int c = blockIdx.x*256 + threadIdx.x;
  if (c >= KEXT) return;
  float sc = 0.f, sh = 0.f;
  if (c < EMBD){
    float mu  = stats[c]*invN;
    float var = stats[EMBD + c]*invN - mu*mu;
    sc = gamma[c]*rsqrtf(var + 1e-5f);
    sh = beta[c] - mu*sc;
  }
  if (c < HROW){ coef[c] = sc; coef[HROW + c] = sh; }
  coefh[c] = (h16)sc; coefh[KEXT + c] = (h16)sh;
}

// ---- fused layer: fixed-8 fan-out gather (affine+relu in-flight) -> MFMA -> BN stats ----
// block = 64 dst rows; wave w owns rows w*16..+15; lane (m16,ko) owns channels
// {k*32+ko*8..+8} of row m16. hRaw = previous layer's RAW lin output (or h0).
// Epilogue stages the C tile in LDS (aliasing Bs) for fully-coalesced row writes.
template<int RELU>
__global__ void __launch_bounds__(256)
k_layer(const h16* __restrict__ hRaw, const h16* __restrict__ coefh,
        const float* __restrict__ dinv,
        const int* __restrict__ offs, const int* __restrict__ counts,
        const int* __restrict__ entries, const h16* __restrict__ Wx,
        h16* __restrict__ hOut, int N, float* __restrict__ stats)
{
  __shared__ h16  smem[64*TS];         // 21.5 KB: Bs (12.8 KB) and C-tile alias
  __shared__ float sred[2*HROW];       //  2.4 KB BN partials
  __shared__ int   rstart[64];
  __shared__ int   rcnt[64];
  __shared__ float dvv[64];
  h16 (*Bs)[BSTR] = (h16(*)[BSTR])smem;
  h16 (*tile)[TS] = (h16(*)[TS])smem;

  int tid = threadIdx.x;
  int wid = tid >> 6, lane = tid & 63;
  int m16 = lane & 15, ko = lane >> 4;
  long row0 = (long)blockIdx.x * 64;

  if (tid < 64){
    long g = row0 + tid;
    int o = 0, c = 0; float d = 0.f;
    if (g < N){ o = offs[g]; c = counts[g]; d = dinv[g]; }
    rstart[tid] = o; rcnt[tid] = c; dvv[tid] = d;
  }
  for (int i = tid; i < 2*HROW; i += 256) sred[i] = 0.f;
  __syncthreads();

  int lr = wid*16 + m16;
  int myStart = rstart[lr], myCnt = rcnt[lr];
  float di = dvv[lr];

  // ---- prefetch up to 8 edge descriptors + weights ----
  int srcA[8]; float wvA[8]; int eA[8];
  #pragma unroll
  for (int j = 0; j < 8; j++){
    int e = entries[myStart + j];               // bounded over-read ok (within ws)
    bool act = j < myCnt;
    int s = act ? (e & 0xFFFFF) : N;            // row N is all-zero
    float wv = dinv[act ? s : 0];
    wvA[j] = act ? wv : 0.f;
    srcA[j] = s; eA[j] = e;
  }
  float ext[8] = {0,0,0,0,0,0,0,0};
  if (ko >= 2){
    int extbase = (ko - 2)*8;
    #pragma unroll
    for (int j = 0; j < 8; j++){
      unsigned msk = 1u | (1u << (1 + ((eA[j] >> 20) & 7))) | (1u << (7 + ((eA[j] >> 23) & 3)));
      #pragma unroll
      for (int c = 0; c < 8; c++)
        ext[c] += ((msk >> (extbase + c)) & 1u) ? wvA[j] : 0.f;
    }
  }
  half8 wvh[8];
  #pragma unroll
  for (int j = 0; j < 8; j++){
    _Float16 w = (_Float16)wvA[j];
    #pragma unroll
    for (int c = 0; c < 8; c++) wvh[j][c] = w;
  }

  half8 acc[10];
  #pragma unroll
  for (int k = 0; k < 10; k++) acc[k] = (half8)(_Float16)0;

  // ---- rare overflow: rows with cnt > 8 (per-lane divergent) ----
  if (__any(myCnt > 8)){
    for (int j = 8; j < myCnt; j++){
      int e = entries[myStart + j];
      int s = e & 0xFFFFF;
      float wv = dinv[s];
      if (ko >= 2){
        int extbase = (ko - 2)*8;
        unsigned msk = 1u | (1u << (1 + ((e >> 20) & 7))) | (1u << (7 + ((e >> 23) & 3)));
        #pragma unroll
        for (int c = 0; c < 8; c++)
          ext[c] += ((msk >> (extbase + c)) & 1u) ? wv : 0.f;
      }
      _Float16 wh = (_Float16)wv;
      half8 w8;
      #pragma unroll
      for (int c = 0; c < 8; c++) w8[c] = wh;
      #pragma unroll
      for (int k = 0; k < 10; k++){
        if (k == 9 && ko >= 2) break;
        half8 sck = *(const half8*)&coefh[k*32 + ko*8];
        half8 shk = *(const half8*)&coefh[KEXT + k*32 + ko*8];
        half8 x = *(const half8*)(hRaw + (size_t)s*HROW + k*32 + ko*8);
        half8 y = sck*x + shk;
        if (RELU){
          #pragma unroll
          for (int c = 0; c < 8; c++) y[c] = y[c] > (_Float16)0 ? y[c] : (_Float16)0;
        }
        acc[k] += w8*y;
      }
    }
  }

  // ---- main gather: chunk-outer, fixed 8 edges inner (8 loads in flight) ----
  #pragma unroll
  for (int k = 0; k < 9; k++){
    half8 sck = *(const half8*)&coefh[k*32 + ko*8];
    half8 shk = *(const half8*)&coefh[KEXT + k*32 + ko*8];
    half8 a = acc[k];
    #pragma unroll
    for (int j = 0; j < 8; j++){
      half8 x = *(const half8*)(hRaw + (size_t)srcA[j]*HROW + k*32 + ko*8);
      half8 y = sck*x + shk;
      if (RELU){
        #pragma unroll
        for (int c = 0; c < 8; c++) y[c] = y[c] > (_Float16)0 ? y[c] : (_Float16)0;
      }
      a += wvh[j]*y;
    }
    acc[k] = a;
  }
  { // k = 9: ko<2 covers cols 288-303 (coef 300-303 = 0); ko>=2 = ext scalars
    half8 a = acc[9];
    if (ko < 2){
      half8 sck = *(const half8*)&coefh[288 + ko*8];
      half8 shk = *(const half8*)&coefh[KEXT + 288 + ko*8];
      #pragma unroll
      for (int j = 0; j < 8; j++){
        half8 x = *(const half8*)(hRaw + (size_t)srcA[j]*HROW + 288 + ko*8);
        half8 y = sck*x + shk;
        if (RELU){
          #pragma unroll
          for (int c = 0; c < 8; c++) y[c] = y[c] > (_Float16)0 ? y[c] : (_Float16)0;
        }
        a += wvh[j]*y;
      }
    } else {
      #pragma unroll
      for (int c = 0; c < 8; c++) a[c] += (_Float16)ext[c];
    }
    acc[9] = a;
  }

  // scale by dinv[dst]
  half8 afr[10];
  {
    _Float16 dh = (_Float16)di;
    half8 d8;
    #pragma unroll
    for (int c = 0; c < 8; c++) d8[c] = dh;
    #pragma unroll
    for (int k = 0; k < 10; k++) afr[k] = acc[k] * d8;
  }

  // ---- GEMM over 2 col-chunks of 160 ----
  int cr = ko * 4;
  #pragma unroll
  for (int jt = 0; jt < 2; jt++){
    f32x4 a2[10];
    #pragma unroll
    for (int j = 0; j < 10; j++) a2[j] = (f32x4){0.f,0.f,0.f,0.f};
    for (int k0 = 0; k0 < 10; k0++){
      __syncthreads();                 // also fences prior tile-writeout reads
      for (int idx = tid; idx < 640; idx += 256){
        int o = idx >> 2, qd = (idx & 3) * 8;
        *(half8*)&Bs[o][qd] = *(const half8*)(Wx + (size_t)(jt*BCH + o)*KEXT + k0*32 + qd);
      }
      __syncthreads();
      #pragma unroll
      for (int j = 0; j < 10; j++){
        half8 bfr = *(const half8*)&Bs[j*16 + m16][ko*8];
        a2[j] = __builtin_amdgcn_mfma_f32_16x16x32_f16(afr[k0], bfr, a2[j], 0, 0, 0);
      }
    }
    // BN partials from registers
    #pragma unroll
    for (int j = 0; j < 10; j++){
      int col = jt*BCH + j*16 + m16;
      float s = 0.f, q = 0.f;
      #pragma unroll
      for (int r = 0; r < 4; r++){
        float v = a2[j][r];
        s += v; q += v*v;
      }
      s += __shfl_xor(s, 16, 64); s += __shfl_xor(s, 32, 64);
      q += __shfl_xor(q, 16, 64); q += __shfl_xor(q, 32, 64);
      if (ko == 0 && col < EMBD){
        atomicAdd(&sred[col], s);
        atomicAdd(&sred[HROW + col], q);
      }
    }
    // stage C tile in LDS (aliases Bs; barrier first so all waves are done with Bs)
    __syncthreads();
    #pragma unroll
    for (int j = 0; j < 10; j++)
      #pragma unroll
      for (int r = 0; r < 4; r++)
        tile[wid*16 + cr + r][j*16 + m16] = (h16)a2[j][r];
    __syncthreads();
    // coalesced writeout: full contiguous row segments (jt0: cols 0-159, jt1: 160-303)
    const int nch = (jt == 0) ? 20 : 18;   // uint4 chunks per row
    for (int idx = tid; idx < 64*nch; idx += 256){
      int row = idx / nch, c = idx - row*nch;
      long grow = row0 + row;
      if (grow < N)
        *(uint4*)(hOut + grow*HROW + jt*BCH + c*8) = *(const uint4*)&tile[row][c*8];
    }
  }
  __syncthreads();
  for (int c = tid; c < EMBD; c += 256){
    atomicAdd(&stats[c], sred[c]);
    atomicAdd(&stats[EMBD + c], sred[HROW + c]);
  }
}

__global__ void k_pool_h(const h16* __restrict__ h, const int* __restrict__ offs,
                         const int* __restrict__ counts, const int* __restrict__ entries,
                         float* __restrict__ out, int M){
  int g = blockIdx.x, t = threadIdx.x, c1 = t + 256;
  int off = offs[g], cnt = counts[g];
  float a0 = 0.f, a1 = 0.f;
  for (int j = 0; j < cnt; j++){
    int r = entries[off + j];
    const h16* hr = h + (size_t)r*HROW;
    a0 += (float)hr[t];
    if (c1 < EMBD) a1 += (float)hr[c1];
  }
  float inv = 1.0f / fmaxf((float)cnt, 1.0f);
  float* o = out + (size_t)g*LDF;
  o[t] = a0*inv;
  if (c1 < EMBD) o[c1] = a1*inv;
}
__global__ void k_pool_f32(const float* __restrict__ h, const int* __restrict__ offs,
                           const int* __restrict__ counts, const int* __restrict__ entries,
                           float* __restrict__ out, int M){
  int g = blockIdx.x, t = threadIdx.x, c1 = t + 256;
  int off = offs[g], cnt = counts[g];
  float a0 = 0.f, a1 = 0.f;
  for (int j = 0; j < cnt; j++){
    int r = entries[off + j];
    const float* hr = h + (size_t)r*LDF;
    a0 += hr[t];
    if (c1 < EMBD) a1 += hr[c1];
  }
  float inv = 1.0f / fmaxf((float)cnt, 1.0f);
  float* o = out + (size_t)g*LDF;
  o[t] = a0*inv;
  if (c1 < EMBD) o[c1] = a1*inv;
}

// pooled rows: v = sc[c]*v + sh[c]  (last-layer BN folded past the mean-pool)
__global__ void k_affine_rows(float* __restrict__ rows, const float* __restrict__ coef, int M){
  int g = blockIdx.x, t = threadIdx.x, c1 = t + 256;
  float* r = rows + (size_t)g*LDF;
  r[t] = coef[t]*r[t] + coef[HROW + t];
  if (c1 < EMBD) r[c1] = coef[c1]*r[c1] + coef[HROW + c1];
}

__global__ void k_mask(float* __restrict__ j, const float* __restrict__ mask,
                       const float* __restrict__ memb, int M){
  int i = blockIdx.x;
  if (mask[i] <= 0.5f) return;
  int t = threadIdx.x, c1 = t + 256;
  float* jr = j + (size_t)i*LDF;
  jr[t] = memb[t];
  if (c1 < EMBD) jr[c1] = memb[c1];
}

__global__ void k_l2norm(float* __restrict__ f, int M){
  int g = blockIdx.x, t = threadIdx.x, c1 = t + 256;
  float* fr = f + (size_t)g*LDF;
  float v0 = fr[t];
  float v1 = (c1 < EMBD) ? fr[c1] : 0.f;
  float ss = v0*v0 + v1*v1;
  #pragma unroll
  for (int o = 32; o > 0; o >>= 1) ss += __shfl_down(ss, o, 64);
  __shared__ float red[4];
  int wid = t >> 6, lane = t & 63;
  if (lane == 0) red[wid] = ss;
  __syncthreads();
  if (t == 0) red[0] = 1.0f / fmaxf(sqrtf(red[0]+red[1]+red[2]+red[3]), 1e-12f);
  __syncthreads();
  float inv = red[0];
  fr[t] = v0*inv;
  if (c1 < EMBD) fr[c1] = v1*inv;
}

// fp32 GEMM for the small junction/logits matmuls
__global__ void __launch_bounds__(256)
k_gemm(const float* __restrict__ A, int lda, const float* __restrict__ W, int ldw,
       const float* __restrict__ bias, const float* __restrict__ e1, const float* __restrict__ e2,
       float* __restrict__ C, int ldc, int M, int Ncols, int K, int relu, float scale){
  __shared__ float As[16][68];
  __shared__ float Ws[16][68];
  int row0 = blockIdx.y * 64, col0 = blockIdx.x * 64;
  int tid = threadIdx.x;
  int tx = tid & 15, ty = tid >> 4;
  float acc[4][4] = {};
  for (int k0 = 0; k0 < K; k0 += 16){
    int r  = tid >> 2;
    int kk = (tid & 3) * 4;
    int gk = k0 + kk;
    float v[4] = {0.f,0.f,0.f,0.f};
    int gr = row0 + r;
    if (gr < M){
      if (gk + 3 < K){ float4 f = *(const float4*)(A + (size_t)gr*lda + gk); v[0]=f.x;v[1]=f.y;v[2]=f.z;v[3]=f.w; }
      else for (int j = 0; j < 4; j++) if (gk + j < K) v[j] = A[(size_t)gr*lda + gk + j];
    }
    As[kk+0][r]=v[0]; As[kk+1][r]=v[1]; As[kk+2][r]=v[2]; As[kk+3][r]=v[3];
    float w[4] = {0.f,0.f,0.f,0.f};
    int o = col0 + r;
    if (o < Ncols){
      if (gk + 3 < K){ float4 f = *(const float4*)(W + (size_t)o*ldw + gk); w[0]=f.x;w[1]=f.y;w[2]=f.z;w[3]=f.w; }
      else for (int j = 0; j < 4; j++) if (gk + j < K) w[j] = W[(size_t)o*ldw + gk + j];
    }
    Ws[kk+0][r]=w[0]; Ws[kk+1][r]=w[1]; Ws[kk+2][r]=w[2]; Ws[kk+3][r]=w[3];
    __syncthreads();
    #pragma unroll
    for (int k = 0; k < 16; k++){
      float4 a4 = *(const float4*)&As[k][ty*4];
      float4 b4 = *(const float4*)&Ws[k][tx*4];
      float a[4] = {a4.x,a4.y,a4.z,a4.w};
      float b[4] = {b4.x,b4.y,b4.z,b4.w};
      #pragma unroll
      for (int i = 0; i < 4; i++)
        #pragma unroll
        for (int j = 0; j < 4; j++) acc[i][j] += a[i]*b[j];
    }
    __syncthreads();
  }
  #pragma unroll
  for (int i = 0; i < 4; i++){
    int rr = row0 + ty*4 + i;
    if (rr >= M) continue;
    #pragma unroll
    for (int j = 0; j < 4; j++){
      int cc = col0 + tx*4 + j;
      if (cc >= Ncols) continue;
      float v = acc[i][j];
      if (bias) v += bias[cc];
      if (e1)   v += e1[cc];
      if (e2)   v += e2[cc];
      v *= scale;
      if (relu) v = fmaxf(v, 0.f);
      C[(size_t)rr*ldc + cc] = v;
    }
  }
}

// ---------------- host side ----------------
static inline void scan_excl(const int* counts, int M, int* offs, int* bsum, hipStream_t s){
  int B = CE(M, 256);
  k_scan_block<<<B,256,0,s>>>(counts, M, offs, bsum);
  k_scan_sums<<<1,1024,0,s>>>(bsum, B);
  k_scan_add<<<B,256,0,s>>>(offs, bsum, M);
}
static inline void gemm_f32(const float* A,int lda,const float* W,int ldw,
                            const float* bias,const float* e1,const float* e2,
                            float* C,int ldc,int M,int Ncols,int K,
                            int relu,float scale,hipStream_t s){
  dim3 grid(CE(Ncols,64), CE(M,64));
  k_gemm<<<grid,256,0,s>>>(A,lda,W,ldw,bias,e1,e2,C,ldc,M,Ncols,K,relu,scale);
}

extern "C" void kernel_launch(void* const* d_in, const int* in_sizes, int n_in,
                              void* d_out, int out_size, void* d_ws, size_t ws_size,
                              hipStream_t stream) {
  const int*   batch_x   = (const int*)d_in[0];
  const int*   batch_ei  = (const int*)d_in[1];
  const int*   batch_ea  = (const int*)d_in[2];
  const int*   batch_gid = (const int*)d_in[3];
  const int*   frag_x    = (const int*)d_in[4];
  const int*   frag_ei   = (const int*)d_in[5];
  const int*   frag_ea   = (const int*)d_in[6];
  const int*   frag_jid  = (const int*)d_in[7];
  const int*   jct_gid   = (const int*)d_in[8];
  const float* jct_mask  = (const float*)d_in[9];
  const float* ae1       = (const float*)d_in[10];
  const float* ae2       = (const float*)d_in[11];
  const float* gnn_W     = (const float*)d_in[12];
  const float* gnn_b     = (const float*)d_in[13];
  const float* gnn_ee1   = (const float*)d_in[14];
  const float* gnn_ee2   = (const float*)d_in[15];
  const float* bn_gamma  = (const float*)d_in[16];
  const float* bn_beta   = (const float*)d_in[17];
  const float* jct_W     = (const float*)d_in[18];
  const float* jct_b     = (const float*)d_in[19];
  const float* jct_ee1   = (const float*)d_in[20];
  const float* jct_ee2   = (const float*)d_in[21];
  const float* mask_emb  = (const float*)d_in[22];

  const int N = in_sizes[0] / 2;       // 200000
  const int E = in_sizes[1] / 2;       // 400000
  const int NG = 1024, NJ = 8192;

  // workspace carve-up (~252 MB)
  size_t off = 0;
  char* base = (char*)d_ws;
  auto carve = [&](size_t bytes) -> void* {
    void* p = base + off;
    off += (bytes + 255) & ~(size_t)255;
    return p;
  };
  h16*  hA      = (h16*) carve((size_t)(N+1) * HROW * 2);   // +1: zero row N
  h16*  hB      = (h16*) carve((size_t)(N+1) * HROW * 2);
  float* dinv    = (float*)carve((size_t)N * 4);
  int*   degcnt  = (int*)  carve((size_t)N * 4);
  int*   cursor  = degcnt;                       // alias: dead after k_dinv
  int*   counts  = (int*)  carve((size_t)N * 4);
  int*   offs    = (int*)  carve((size_t)(N + 1) * 4);
  int*   entries = (int*)  carve((size_t)(E + N) * 4);
  int*   bsum    = (int*)  carve(1024 * 4);
  float* stats   = (float*)carve(2 * EMBD * 4);
  float* coef    = (float*)carve(2 * HROW * 4);
  float* idcoef  = (float*)carve(2 * HROW * 4);
  h16*  coefh   = (h16*) carve(2 * KEXT * 2);
  h16*  idcoefh = (h16*) carve(2 * KEXT * 2);
  h16*  wext    = (h16*) carve((size_t)5 * KEXT * KEXT * 2);
  float* f0      = (float*)carve((size_t)NG * LDF * 4);
  float* f1      = (float*)carve((size_t)NG * LDF * 4);
  size_t required = off;
  // junction-phase fp32 buffers alias hA (dead when used)
  float* g0      = (float*)hA;
  float* t1      = (float*)((char*)hA + ((size_t)16 << 20));
  float* t2      = (float*)((char*)hA + ((size_t)32 << 20));
  (void)n_in;

  if (ws_size < required || d_ws == nullptr){
    float v = 1.0e6f + (float)(ws_size >> 20) * 1000.0f;   // encode ws MB in absmax
    k_diag<<<CE(out_size,256),256,0,stream>>>((float*)d_out, out_size, v);
    return;
  }

  // one-time prep: extended fp16 weights; identity coef; zero row N of both h buffers
  { dim3 g(KEXT, 5); k_wext<<<g,256,0,stream>>>(gnn_W, gnn_b, gnn_ee1, gnn_ee2, wext); }
  k_id_coef<<<CE(KEXT,256),256,0,stream>>>(idcoef, idcoefh);
  hipMemsetAsync(hA + (size_t)N*HROW, 0, HROW*2, stream);
  hipMemsetAsync(hB + (size_t)N*HROW, 0, HROW*2, stream);

  const int LBLK = CE(N, 64);   // fused-layer grid

  for (int br = 0; br < 2; br++){
    const int* x  = br ? frag_x  : batch_x;
    const int* ei = br ? frag_ei : batch_ei;
    const int* ea = br ? frag_ea : batch_ea;

    // degree (by src, +1 self-loop) -> dinv
    hipMemsetAsync(degcnt, 0, (size_t)N*4, stream);
    k_count_src<<<CE(E,256),256,0,stream>>>(ei, E, degcnt);
    k_dinv<<<CE(N,256),256,0,stream>>>(degcnt, dinv, N);

    // dst-CSR over E real edges + N self-loops (layer-invariant)
    k_set_val<<<CE(N,256),256,0,stream>>>(counts, N, 1);
    k_count_dst<<<CE(E,256),256,0,stream>>>(ei, E, counts);
    scan_excl(counts, N, offs, bsum, stream);
    hipMemsetAsync(cursor, 0, (size_t)N*4, stream);
    k_fill_edges<<<CE(E+N,256),256,0,stream>>>(ei, ea, E, N, offs, cursor, entries);

    // h0 raw = ae1[x0] + ae2[x1]
    k_init_h0<<<N,256,0,stream>>>(x, ae1, ae2, hA, N);

    // 5 fused layers, ping-pong; BN affine+relu applied in the NEXT layer's gather
    for (int l = 0; l < 5; l++){
      const h16* src = (l & 1) ? hB : hA;
      h16*       dst = (l & 1) ? hA : hB;
      const h16* ch  = (l == 0) ? idcoefh : coefh;
      hipMemsetAsync(stats, 0, 2*EMBD*4, stream);
      if (l == 0)
        k_layer<0><<<LBLK,256,0,stream>>>(src, ch, dinv, offs, counts, entries,
                                          wext + (size_t)l*KEXT*KEXT, dst, N, stats);
      else
        k_layer<1><<<LBLK,256,0,stream>>>(src, ch, dinv, offs, counts, entries,
                                          wext + (size_t)l*KEXT*KEXT, dst, N, stats);
      k_bn_coef<<<CE(KEXT,256),256,0,stream>>>(stats, bn_gamma + l*EMBD, bn_beta + l*EMBD,
                                               coef, coefh, 1.0f/(float)N);
    }
    // hB holds raw layer-4 lin output; coef holds its BN affine (no relu on last layer):
    // BN commutes with mean-pool -> apply affine on pooled rows.

    if (br == 0){
      hipMemsetAsync(counts, 0, (size_t)NG*4, stream);
      k_count_ids<<<CE(N,256),256,0,stream>>>(batch_gid, N, counts);
      scan_excl(counts, NG, offs, bsum, stream);
      hipMemsetAsync(cursor, 0, (size_t)NG*4, stream);
      k_fill_rows<<<CE(N,256),256,0,stream>>>(batch_gid, N, offs, cursor, entries);
      k_pool_h<<<NG,256,0,stream>>>(hB, offs, counts, entries, g0, NG);
      k_affine_rows<<<NG,256,0,stream>>>(g0, coef, NG);
      gemm_f32(g0, LDF, jct_W, EMBD, jct_b,
               jct_ee1 + 4*EMBD, jct_ee2,
               t1, LDF, NG, EMBD, EMBD, 1, 1.0f, stream);
      gemm_f32(t1, LDF, jct_W + EMBD*EMBD, EMBD, jct_b + EMBD,
               jct_ee1 + 6*EMBD + 4*EMBD, jct_ee2 + 3*EMBD,
               f0, LDF, NG, EMBD, EMBD, 0, 1.0f, stream);
      k_l2norm<<<NG,256,0,stream>>>(f0, NG);
    } else {
      hipMemsetAsync(counts, 0, (size_t)NJ*4, stream);
      k_count_ids<<<CE(N,256),256,0,stream>>>(frag_jid, N, counts);
      scan_excl(counts, NJ, offs, bsum, stream);
      hipMemsetAsync(cursor, 0, (size_t)NJ*4, stream);
      k_fill_rows<<<CE(N,256),256,0,stream>>>(frag_jid, N, offs, cursor, entries);
      k_pool_h<<<NJ,256,0,stream>>>(hB, offs, counts, entries, t1, NJ);
      k_affine_rows<<<NJ,256,0,stream>>>(t1, coef, NJ);
      k_mask<<<NJ,256,0,stream>>>(t1, jct_mask, mask_emb, NJ);
      gemm_f32(t1, LDF, jct_W, EMBD, jct_b,
               jct_ee1 + 4*EMBD, jct_ee2,
               t2, LDF, NJ, EMBD, EMBD, 1, 1.0f, stream);
      gemm_f32(t2, LDF, jct_W + EMBD*EMBD, EMBD, jct_b + EMBD,
               jct_ee1 + 6*EMBD + 4*EMBD, jct_ee2 + 3*EMBD,
               t1, LDF, NJ, EMBD, EMBD, 0, 1.0f, stream);
      hipMemsetAsync(counts, 0, (size_t)NG*4, stream);
      k_count_ids<<<CE(NJ,256),256,0,stream>>>(jct_gid, NJ, counts);
      scan_excl(counts, NG, offs, bsum, stream);
      hipMemsetAsync(cursor, 0, (size_t)NG*4, stream);
      k_fill_rows<<<CE(NJ,256),256,0,stream>>>(jct_gid, NJ, offs, cursor, entries);
      k_pool_f32<<<NG,256,0,stream>>>(t1, offs, counts, entries, f1, NG);
      k_l2norm<<<NG,256,0,stream>>>(f1, NG);
    }
  }

  // logits = (f0 @ f1^T) / TEMP
  gemm_f32(f0, LDF, f1, LDF, nullptr, nullptr, nullptr,
           (float*)d_out, 1024, NG, NG, EMBD, 0, 25.0f, stream);
}

// Round 11
// 4074.508 us; speedup vs baseline: 1.3947x; 1.0528x over previous
//
#include <hip/hip_runtime.h>
#include <math.h>

#define EMBD 300
#define HROW 304     // fp16 h row stride (elements) = 608 B; cols 300-303 = 0
#define LDF  304     // fp32 junction-phase row stride
#define KEXT 320     // extended K: 304 h(+pad) + 1 bias + 6 ee1 + 3 ee2 + 6 pad
#define BCH  80      // B cols per jt chunk (4 chunks of 80 = 320)
#define BSTR 40      // LDS B row stride (halves): 80 B
#define TS2  312     // LDS C-tile row stride (halves): 624 B
#define CE(a,b) (((a)+(b)-1)/(b))

typedef _Float16 h16;
typedef __attribute__((ext_vector_type(8))) _Float16 half8;
typedef __attribute__((ext_vector_type(4))) float f32x4;

// ---------------- utility / CSR kernels ----------------
__global__ void k_diag(float* out, int n, float v){
  int i = blockIdx.x*256 + threadIdx.x;
  if (i < n) out[i] = v;
}
__global__ void k_set_val(int* p, int n, int v){
  int i = blockIdx.x*256 + threadIdx.x;
  if (i < n) p[i] = v;
}
__global__ void k_count_src(const int* __restrict__ ei, int E, int* __restrict__ deg){
  int e = blockIdx.x*256 + threadIdx.x;
  if (e < E) atomicAdd(&deg[ei[e]], 1);
}
__global__ void k_dinv(const int* __restrict__ deg, float* __restrict__ dinv, int N){
  int i = blockIdx.x*256 + threadIdx.x;
  if (i < N) dinv[i] = 1.0f / sqrtf((float)(deg[i] + 1));   // +1 self-loop
}
__global__ void k_count_dst(const int* __restrict__ ei, int E, int* __restrict__ counts){
  int e = blockIdx.x*256 + threadIdx.x;
  if (e < E) atomicAdd(&counts[ei[E + e]], 1);
}
__global__ void k_count_ids(const int* __restrict__ ids, int n, int* __restrict__ counts){
  int i = blockIdx.x*256 + threadIdx.x;
  if (i < n) atomicAdd(&counts[ids[i]], 1);
}
__global__ void k_scan_block(const int* __restrict__ in, int M, int* __restrict__ out, int* __restrict__ bsum){
  __shared__ int s[256];
  int t = threadIdx.x, i = blockIdx.x*256 + t;
  int v = (i < M) ? in[i] : 0;
  s[t] = v; __syncthreads();
  for (int off = 1; off < 256; off <<= 1){
    int x = (t >= off) ? s[t-off] : 0;
    __syncthreads();
    s[t] += x;
    __syncthreads();
  }
  if (i < M) out[i] = s[t] - v;
  if (t == 255) bsum[blockIdx.x] = s[255];
}
__global__ void k_scan_sums(int* __restrict__ bsum, int B){   // B <= 1024
  __shared__ int s[1024];
  int t = threadIdx.x;
  int v = (t < B) ? bsum[t] : 0;
  s[t] = v; __syncthreads();
  for (int off = 1; off < 1024; off <<= 1){
    int x = (t >= off) ? s[t-off] : 0;
    __syncthreads();
    s[t] += x;
    __syncthreads();
  }
  if (t < B) bsum[t] = s[t] - v;
}
__global__ void k_scan_add(int* __restrict__ out, const int* __restrict__ bsum, int M){
  int i = blockIdx.x*256 + threadIdx.x;
  if (i < M) out[i] += bsum[blockIdx.x];
}
// entries payload: src | bt<<20 | bd<<23   (src < 2^20)
__global__ void k_fill_edges(const int* __restrict__ ei, const int* __restrict__ ea, int E, int N,
                             const int* __restrict__ offs, int* __restrict__ cur, int* __restrict__ entries){
  int e = blockIdx.x*256 + threadIdx.x;
  if (e < E){
    int s  = ei[e];
    int d  = ei[E + e];
    int bt = ea[2*e], bd = ea[2*e + 1];
    int pos = offs[d] + atomicAdd(&cur[d], 1);
    entries[pos] = s | (bt << 20) | (bd << 23);
  } else if (e < E + N){
    int i = e - E;                          // self-loop: bond type 4, dir 0
    int pos = offs[i] + atomicAdd(&cur[i], 1);
    entries[pos] = i | (4 << 20);
  }
}
__global__ void k_fill_rows(const int* __restrict__ ids, int n, const int* __restrict__ offs,
                            int* __restrict__ cur, int* __restrict__ entries){
  int i = blockIdx.x*256 + threadIdx.x;
  if (i < n){
    int g = ids[i];
    int pos = offs[g] + atomicAdd(&cur[g], 1);
    entries[pos] = i;
  }
}

// ---------------- model kernels ----------------
// h0: raw fp16 embeddings, cols 300-303 = 0
__global__ void k_init_h0(const int* __restrict__ x, const float* __restrict__ ae1,
                          const float* __restrict__ ae2, h16* __restrict__ h, int N){
  int i = blockIdx.x, t = threadIdx.x;
  int a = x[2*i], b = x[2*i + 1];
  const float* e1 = ae1 + (size_t)a*EMBD;
  const float* e2 = ae2 + (size_t)b*EMBD;
  h16* hr = h + (size_t)i*HROW;
  hr[t] = (h16)(e1[t] + e2[t]);
  int c = t + 256;
  if (c < HROW) hr[c] = (c < EMBD) ? (h16)(e1[c] + e2[c]) : (h16)0.f;
}

// extended weights (fp16): Wx[l][o][k], o,k in [0,KEXT)
// k<300: W[o][k]; k==304: b[o]; 305..310: ee1; 311..313: ee2; else 0
__global__ void k_wext(const float* __restrict__ W, const float* __restrict__ b,
                       const float* __restrict__ ee1, const float* __restrict__ ee2,
                       h16* __restrict__ out){
  int l = blockIdx.y, o = blockIdx.x, t = threadIdx.x;
  h16* d = out + ((size_t)l*KEXT + o)*KEXT;
  for (int k = t; k < KEXT; k += 256){
    float v = 0.f;
    if (o < EMBD){
      if      (k < EMBD)            v = W[(size_t)l*EMBD*EMBD + (size_t)o*EMBD + k];
      else if (k == 304)            v = b[l*EMBD + o];
      else if (k >= 305 && k < 311) v = ee1[((size_t)l*6 + (k-305))*EMBD + o];
      else if (k >= 311 && k < 314) v = ee2[((size_t)l*3 + (k-311))*EMBD + o];
    }
    d[k] = (h16)v;
  }
}

__global__ void k_id_coef(float* coef, h16* coefh){
  int c = blockIdx.x*256 + threadIdx.x;
  if (c < HROW){
    coef[c] = (c < EMBD) ? 1.f : 0.f;
    coef[HROW + c] = 0.f;
  }
  if (c < KEXT){
    coefh[c] = (c < EMBD) ? (h16)1.f : (h16)0.f;
    coefh[KEXT + c] = (h16)0.f;
  }
}
// BN affine from stats: fp32 (for pooled rows) + fp16 (for gather)
__global__ void k_bn_coef(const float* __restrict__ stats, const float* __restrict__ gamma,
                          const float* __restrict__ beta, float* __restrict__ coef,
                          h16* __restrict__ coefh, float invN){
  int c = blockIdx.x*256 + threadIdx.x;
  if (c >= KEXT) return;
  float sc = 0.f, sh = 0.f;
  if (c < EMBD){
    float mu  = stats[c]*invN;
    float var = stats[EMBD + c]*invN - mu*mu;
    sc = gamma[c]*rsqrtf(var + 1e-5f);
    sh = beta[c] - mu*sc;
  }
  if (c < HROW){ coef[c] = sc; coef[HROW + c] = sh; }
  coefh[c] = (h16)sc; coefh[KEXT + c] = (h16)sh;
}

// ---- fused layer: fixed-8 fan-out gather (affine+relu in-flight) -> MFMA -> BN stats ----
// block = 64 dst rows; wave w owns rows w*16..+15; lane (m16,ko) owns channels
// {k*32+ko*8..+8} of row m16. C tile persists in LDS; ONE full-row coalesced
// writeout at the end (each 64B line written exactly once).
template<int RELU>
__global__ void __launch_bounds__(256)
k_layer(const h16* __restrict__ hRaw, const h16* __restrict__ coefh,
        const float* __restrict__ dinv,
        const int* __restrict__ offs, const int* __restrict__ counts,
        const int* __restrict__ entries, const h16* __restrict__ Wx,
        h16* __restrict__ hOut, int N, float* __restrict__ stats)
{
  __shared__ h16  tile[64][TS2];       // 39.9 KB persistent C tile
  __shared__ h16  Bs[BCH][BSTR];       //  6.4 KB B chunk (80 cols x 32 k)
  __shared__ float sred[2*HROW];       //  2.4 KB BN partials
  __shared__ int   rstart[64];
  __shared__ int   rcnt[64];
  __shared__ float dvv[64];

  int tid = threadIdx.x;
  int wid = tid >> 6, lane = tid & 63;
  int m16 = lane & 15, ko = lane >> 4;
  long row0 = (long)blockIdx.x * 64;

  if (tid < 64){
    long g = row0 + tid;
    int o = 0, c = 0; float d = 0.f;
    if (g < N){ o = offs[g]; c = counts[g]; d = dinv[g]; }
    rstart[tid] = o; rcnt[tid] = c; dvv[tid] = d;
  }
  for (int i = tid; i < 2*HROW; i += 256) sred[i] = 0.f;
  __syncthreads();

  int lr = wid*16 + m16;
  int myStart = rstart[lr], myCnt = rcnt[lr];
  float di = dvv[lr];

  // ---- prefetch up to 8 edge descriptors + weights ----
  int srcA[8]; float wvA[8]; int eA[8];
  #pragma unroll
  for (int j = 0; j < 8; j++){
    int e = entries[myStart + j];               // bounded over-read ok (within ws)
    bool act = j < myCnt;
    int s = act ? (e & 0xFFFFF) : N;            // row N is all-zero
    float wv = dinv[act ? s : 0];
    wvA[j] = act ? wv : 0.f;
    srcA[j] = s; eA[j] = e;
  }
  float ext[8] = {0,0,0,0,0,0,0,0};
  if (ko >= 2){
    int extbase = (ko - 2)*8;
    #pragma unroll
    for (int j = 0; j < 8; j++){
      unsigned msk = 1u | (1u << (1 + ((eA[j] >> 20) & 7))) | (1u << (7 + ((eA[j] >> 23) & 3)));
      #pragma unroll
      for (int c = 0; c < 8; c++)
        ext[c] += ((msk >> (extbase + c)) & 1u) ? wvA[j] : 0.f;
    }
  }
  half8 wvh[8];
  #pragma unroll
  for (int j = 0; j < 8; j++){
    _Float16 w = (_Float16)wvA[j];
    #pragma unroll
    for (int c = 0; c < 8; c++) wvh[j][c] = w;
  }

  half8 acc[10];
  #pragma unroll
  for (int k = 0; k < 10; k++) acc[k] = (half8)(_Float16)0;

  // ---- rare overflow: rows with cnt > 8 (per-lane divergent) ----
  if (__any(myCnt > 8)){
    for (int j = 8; j < myCnt; j++){
      int e = entries[myStart + j];
      int s = e & 0xFFFFF;
      float wv = dinv[s];
      if (ko >= 2){
        int extbase = (ko - 2)*8;
        unsigned msk = 1u | (1u << (1 + ((e >> 20) & 7))) | (1u << (7 + ((e >> 23) & 3)));
        #pragma unroll
        for (int c = 0; c < 8; c++)
          ext[c] += ((msk >> (extbase + c)) & 1u) ? wv : 0.f;
      }
      _Float16 wh = (_Float16)wv;
      half8 w8;
      #pragma unroll
      for (int c = 0; c < 8; c++) w8[c] = wh;
      #pragma unroll
      for (int k = 0; k < 10; k++){
        if (k == 9 && ko >= 2) break;
        half8 sck = *(const half8*)&coefh[k*32 + ko*8];
        half8 shk = *(const half8*)&coefh[KEXT + k*32 + ko*8];
        half8 x = *(const half8*)(hRaw + (size_t)s*HROW + k*32 + ko*8);
        half8 y = sck*x + shk;
        if (RELU){
          #pragma unroll
          for (int c = 0; c < 8; c++) y[c] = y[c] > (_Float16)0 ? y[c] : (_Float16)0;
        }
        acc[k] += w8*y;
      }
    }
  }

  // ---- main gather: chunk-outer, fixed 8 edges inner (8 loads in flight) ----
  #pragma unroll
  for (int k = 0; k < 9; k++){
    half8 sck = *(const half8*)&coefh[k*32 + ko*8];
    half8 shk = *(const half8*)&coefh[KEXT + k*32 + ko*8];
    half8 a = acc[k];
    #pragma unroll
    for (int j = 0; j < 8; j++){
      half8 x = *(const half8*)(hRaw + (size_t)srcA[j]*HROW + k*32 + ko*8);
      half8 y = sck*x + shk;
      if (RELU){
        #pragma unroll
        for (int c = 0; c < 8; c++) y[c] = y[c] > (_Float16)0 ? y[c] : (_Float16)0;
      }
      a += wvh[j]*y;
    }
    acc[k] = a;
  }
  { // k = 9: ko<2 covers cols 288-303 (coef 300-303 = 0); ko>=2 = ext scalars
    half8 a = acc[9];
    if (ko < 2){
      half8 sck = *(const half8*)&coefh[288 + ko*8];
      half8 shk = *(const half8*)&coefh[KEXT + 288 + ko*8];
      #pragma unroll
      for (int j = 0; j < 8; j++){
        half8 x = *(const half8*)(hRaw + (size_t)srcA[j]*HROW + 288 + ko*8);
        half8 y = sck*x + shk;
        if (RELU){
          #pragma unroll
          for (int c = 0; c < 8; c++) y[c] = y[c] > (_Float16)0 ? y[c] : (_Float16)0;
        }
        a += wvh[j]*y;
      }
    } else {
      #pragma unroll
      for (int c = 0; c < 8; c++) a[c] += (_Float16)ext[c];
    }
    acc[9] = a;
  }

  // scale by dinv[dst]
  half8 afr[10];
  {
    _Float16 dh = (_Float16)di;
    half8 d8;
    #pragma unroll
    for (int c = 0; c < 8; c++) d8[c] = dh;
    #pragma unroll
    for (int k = 0; k < 10; k++) afr[k] = acc[k] * d8;
  }

  // ---- GEMM over 4 col-chunks of 80; C staged to persistent LDS tile ----
  int cr = ko * 4;
  #pragma unroll
  for (int jt = 0; jt < 4; jt++){
    f32x4 a2[5];
    #pragma unroll
    for (int j = 0; j < 5; j++) a2[j] = (f32x4){0.f,0.f,0.f,0.f};
    for (int k0 = 0; k0 < 10; k0++){
      __syncthreads();
      for (int idx = tid; idx < 320; idx += 256){
        int o = idx >> 2, qd = (idx & 3) * 8;
        *(half8*)&Bs[o][qd] = *(const half8*)(Wx + (size_t)(jt*BCH + o)*KEXT + k0*32 + qd);
      }
      __syncthreads();
      #pragma unroll
      for (int j = 0; j < 5; j++){
        half8 bfr = *(const half8*)&Bs[j*16 + m16][ko*8];
        a2[j] = __builtin_amdgcn_mfma_f32_16x16x32_f16(afr[k0], bfr, a2[j], 0, 0, 0);
      }
    }
    // BN partials from registers
    #pragma unroll
    for (int j = 0; j < 5; j++){
      int col = jt*BCH + j*16 + m16;
      float s = 0.f, q = 0.f;
      #pragma unroll
      for (int r = 0; r < 4; r++){
        float v = a2[j][r];
        s += v; q += v*v;
      }
      s += __shfl_xor(s, 16, 64); s += __shfl_xor(s, 32, 64);
      q += __shfl_xor(q, 16, 64); q += __shfl_xor(q, 32, 64);
      if (ko == 0 && col < EMBD){
        atomicAdd(&sred[col], s);
        atomicAdd(&sred[HROW + col], q);
      }
    }
    // stage to tile (wave-private rows: no barrier needed)
    #pragma unroll
    for (int j = 0; j < 5; j++){
      int col = jt*BCH + j*16 + m16;
      if (col < HROW){
        #pragma unroll
        for (int r = 0; r < 4; r++)
          tile[wid*16 + cr + r][col] = (h16)a2[j][r];
      }
    }
  }
  __syncthreads();
  // ---- single coalesced writeout: full 608 B rows, each line written once ----
  for (int idx = tid; idx < 64*38; idx += 256){
    int row = idx / 38, c = idx - row*38;
    long grow = row0 + row;
    if (grow < N)
      *(uint4*)(hOut + grow*HROW + c*8) = *(const uint4*)&tile[row][c*8];
  }
  __syncthreads();
  for (int c = tid; c < EMBD; c += 256){
    atomicAdd(&stats[c], sred[c]);
    atomicAdd(&stats[EMBD + c], sred[HROW + c]);
  }
}

__global__ void k_pool_h(const h16* __restrict__ h, const int* __restrict__ offs,
                         const int* __restrict__ counts, const int* __restrict__ entries,
                         float* __restrict__ out, int M){
  int g = blockIdx.x, t = threadIdx.x, c1 = t + 256;
  int off = offs[g], cnt = counts[g];
  float a0 = 0.f, a1 = 0.f;
  for (int j = 0; j < cnt; j++){
    int r = entries[off + j];
    const h16* hr = h + (size_t)r*HROW;
    a0 += (float)hr[t];
    if (c1 < EMBD) a1 += (float)hr[c1];
  }
  float inv = 1.0f / fmaxf((float)cnt, 1.0f);
  float* o = out + (size_t)g*LDF;
  o[t] = a0*inv;
  if (c1 < EMBD) o[c1] = a1*inv;
}
__global__ void k_pool_f32(const float* __restrict__ h, const int* __restrict__ offs,
                           const int* __restrict__ counts, const int* __restrict__ entries,
                           float* __restrict__ out, int M){
  int g = blockIdx.x, t = threadIdx.x, c1 = t + 256;
  int off = offs[g], cnt = counts[g];
  float a0 = 0.f, a1 = 0.f;
  for (int j = 0; j < cnt; j++){
    int r = entries[off + j];
    const float* hr = h + (size_t)r*LDF;
    a0 += hr[t];
    if (c1 < EMBD) a1 += hr[c1];
  }
  float inv = 1.0f / fmaxf((float)cnt, 1.0f);
  float* o = out + (size_t)g*LDF;
  o[t] = a0*inv;
  if (c1 < EMBD) o[c1] = a1*inv;
}

// pooled rows: v = sc[c]*v + sh[c]  (last-layer BN folded past the mean-pool)
__global__ void k_affine_rows(float* __restrict__ rows, const float* __restrict__ coef, int M){
  int g = blockIdx.x, t = threadIdx.x, c1 = t + 256;
  float* r = rows + (size_t)g*LDF;
  r[t] = coef[t]*r[t] + coef[HROW + t];
  if (c1 < EMBD) r[c1] = coef[c1]*r[c1] + coef[HROW + c1];
}

__global__ void k_mask(float* __restrict__ j, const float* __restrict__ mask,
                       const float* __restrict__ memb, int M){
  int i = blockIdx.x;
  if (mask[i] <= 0.5f) return;
  int t = threadIdx.x, c1 = t + 256;
  float* jr = j + (size_t)i*LDF;
  jr[t] = memb[t];
  if (c1 < EMBD) jr[c1] = memb[c1];
}

__global__ void k_l2norm(float* __restrict__ f, int M){
  int g = blockIdx.x, t = threadIdx.x, c1 = t + 256;
  float* fr = f + (size_t)g*LDF;
  float v0 = fr[t];
  float v1 = (c1 < EMBD) ? fr[c1] : 0.f;
  float ss = v0*v0 + v1*v1;
  #pragma unroll
  for (int o = 32; o > 0; o >>= 1) ss += __shfl_down(ss, o, 64);
  __shared__ float red[4];
  int wid = t >> 6, lane = t & 63;
  if (lane == 0) red[wid] = ss;
  __syncthreads();
  if (t == 0) red[0] = 1.0f / fmaxf(sqrtf(red[0]+red[1]+red[2]+red[3]), 1e-12f);
  __syncthreads();
  float inv = red[0];
  fr[t] = v0*inv;
  if (c1 < EMBD) fr[c1] = v1*inv;
}

// fp32 GEMM for the small junction/logits matmuls
__global__ void __launch_bounds__(256)
k_gemm(const float* __restrict__ A, int lda, const float* __restrict__ W, int ldw,
       const float* __restrict__ bias, const float* __restrict__ e1, const float* __restrict__ e2,
       float* __restrict__ C, int ldc, int M, int Ncols, int K, int relu, float scale){
  __shared__ float As[16][68];
  __shared__ float Ws[16][68];
  int row0 = blockIdx.y * 64, col0 = blockIdx.x * 64;
  int tid = threadIdx.x;
  int tx = tid & 15, ty = tid >> 4;
  float acc[4][4] = {};
  for (int k0 = 0; k0 < K; k0 += 16){
    int r  = tid >> 2;
    int kk = (tid & 3) * 4;
    int gk = k0 + kk;
    float v[4] = {0.f,0.f,0.f,0.f};
    int gr = row0 + r;
    if (gr < M){
      if (gk + 3 < K){ float4 f = *(const float4*)(A + (size_t)gr*lda + gk); v[0]=f.x;v[1]=f.y;v[2]=f.z;v[3]=f.w; }
      else for (int j = 0; j < 4; j++) if (gk + j < K) v[j] = A[(size_t)gr*lda + gk + j];
    }
    As[kk+0][r]=v[0]; As[kk+1][r]=v[1]; As[kk+2][r]=v[2]; As[kk+3][r]=v[3];
    float w[4] = {0.f,0.f,0.f,0.f};
    int o = col0 + r;
    if (o < Ncols){
      if (gk + 3 < K){ float4 f = *(const float4*)(W + (size_t)o*ldw + gk); w[0]=f.x;w[1]=f.y;w[2]=f.z;w[3]=f.w; }
      else for (int j = 0; j < 4; j++) if (gk + j < K) w[j] = W[(size_t)o*ldw + gk + j];
    }
    Ws[kk+0][r]=w[0]; Ws[kk+1][r]=w[1]; Ws[kk+2][r]=w[2]; Ws[kk+3][r]=w[3];
    __syncthreads();
    #pragma unroll
    for (int k = 0; k < 16; k++){
      float4 a4 = *(const float4*)&As[k][ty*4];
      float4 b4 = *(const float4*)&Ws[k][tx*4];
      float a[4] = {a4.x,a4.y,a4.z,a4.w};
      float b[4] = {b4.x,b4.y,b4.z,b4.w};
      #pragma unroll
      for (int i = 0; i < 4; i++)
        #pragma unroll
        for (int j = 0; j < 4; j++) acc[i][j] += a[i]*b[j];
    }
    __syncthreads();
  }
  #pragma unroll
  for (int i = 0; i < 4; i++){
    int rr = row0 + ty*4 + i;
    if (rr >= M) continue;
    #pragma unroll
    for (int j = 0; j < 4; j++){
      int cc = col0 + tx*4 + j;
      if (cc >= Ncols) continue;
      float v = acc[i][j];
      if (bias) v += bias[cc];
      if (e1)   v += e1[cc];
      if (e2)   v += e2[cc];
      v *= scale;
      if (relu) v = fmaxf(v, 0.f);
      C[(size_t)rr*ldc + cc] = v;
    }
  }
}

// ---------------- host side ----------------
static inline void scan_excl(const int* counts, int M, int* offs, int* bsum, hipStream_t s){
  int B = CE(M, 256);
  k_scan_block<<<B,256,0,s>>>(counts, M, offs, bsum);
  k_scan_sums<<<1,1024,0,s>>>(bsum, B);
  k_scan_add<<<B,256,0,s>>>(offs, bsum, M);
}
static inline void gemm_f32(const float* A,int lda,const float* W,int ldw,
                            const float* bias,const float* e1,const float* e2,
                            float* C,int ldc,int M,int Ncols,int K,
                            int relu,float scale,hipStream_t s){
  dim3 grid(CE(Ncols,64), CE(M,64));
  k_gemm<<<grid,256,0,s>>>(A,lda,W,ldw,bias,e1,e2,C,ldc,M,Ncols,K,relu,scale);
}

extern "C" void kernel_launch(void* const* d_in, const int* in_sizes, int n_in,
                              void* d_out, int out_size, void* d_ws, size_t ws_size,
                              hipStream_t stream) {
  const int*   batch_x   = (const int*)d_in[0];
  const int*   batch_ei  = (const int*)d_in[1];
  const int*   batch_ea  = (const int*)d_in[2];
  const int*   batch_gid = (const int*)d_in[3];
  const int*   frag_x    = (const int*)d_in[4];
  const int*   frag_ei   = (const int*)d_in[5];
  const int*   frag_ea   = (const int*)d_in[6];
  const int*   frag_jid  = (const int*)d_in[7];
  const int*   jct_gid   = (const int*)d_in[8];
  const float* jct_mask  = (const float*)d_in[9];
  const float* ae1       = (const float*)d_in[10];
  const float* ae2       = (const float*)d_in[11];
  const float* gnn_W     = (const float*)d_in[12];
  const float* gnn_b     = (const float*)d_in[13];
  const float* gnn_ee1   = (const float*)d_in[14];
  const float* gnn_ee2   = (const float*)d_in[15];
  const float* bn_gamma  = (const float*)d_in[16];
  const float* bn_beta   = (const float*)d_in[17];
  const float* jct_W     = (const float*)d_in[18];
  const float* jct_b     = (const float*)d_in[19];
  const float* jct_ee1   = (const float*)d_in[20];
  const float* jct_ee2   = (const float*)d_in[21];
  const float* mask_emb  = (const float*)d_in[22];

  const int N = in_sizes[0] / 2;       // 200000
  const int E = in_sizes[1] / 2;       // 400000
  const int NG = 1024, NJ = 8192;

  // workspace carve-up (~252 MB)
  size_t off = 0;
  char* base = (char*)d_ws;
  auto carve = [&](size_t bytes) -> void* {
    void* p = base + off;
    off += (bytes + 255) & ~(size_t)255;
    return p;
  };
  h16*  hA      = (h16*) carve((size_t)(N+1) * HROW * 2);   // +1: zero row N
  h16*  hB      = (h16*) carve((size_t)(N+1) * HROW * 2);
  float* dinv    = (float*)carve((size_t)N * 4);
  int*   degcnt  = (int*)  carve((size_t)N * 4);
  int*   cursor  = degcnt;                       // alias: dead after k_dinv
  int*   counts  = (int*)  carve((size_t)N * 4);
  int*   offs    = (int*)  carve((size_t)(N + 1) * 4);
  int*   entries = (int*)  carve((size_t)(E + N) * 4);
  int*   bsum    = (int*)  carve(1024 * 4);
  float* stats   = (float*)carve(2 * EMBD * 4);
  float* coef    = (float*)carve(2 * HROW * 4);
  float* idcoef  = (float*)carve(2 * HROW * 4);
  h16*  coefh   = (h16*) carve(2 * KEXT * 2);
  h16*  idcoefh = (h16*) carve(2 * KEXT * 2);
  h16*  wext    = (h16*) carve((size_t)5 * KEXT * KEXT * 2);
  float* f0      = (float*)carve((size_t)NG * LDF * 4);
  float* f1      = (float*)carve((size_t)NG * LDF * 4);
  size_t required = off;
  // junction-phase fp32 buffers alias hA (dead when used)
  float* g0      = (float*)hA;
  float* t1      = (float*)((char*)hA + ((size_t)16 << 20));
  float* t2      = (float*)((char*)hA + ((size_t)32 << 20));
  (void)n_in;

  if (ws_size < required || d_ws == nullptr){
    float v = 1.0e6f + (float)(ws_size >> 20) * 1000.0f;   // encode ws MB in absmax
    k_diag<<<CE(out_size,256),256,0,stream>>>((float*)d_out, out_size, v);
    return;
  }

  // one-time prep: extended fp16 weights; identity coef; zero row N of both h buffers
  { dim3 g(KEXT, 5); k_wext<<<g,256,0,stream>>>(gnn_W, gnn_b, gnn_ee1, gnn_ee2, wext); }
  k_id_coef<<<CE(KEXT,256),256,0,stream>>>(idcoef, idcoefh);
  hipMemsetAsync(hA + (size_t)N*HROW, 0, HROW*2, stream);
  hipMemsetAsync(hB + (size_t)N*HROW, 0, HROW*2, stream);

  const int LBLK = CE(N, 64);   // fused-layer grid

  for (int br = 0; br < 2; br++){
    const int* x  = br ? frag_x  : batch_x;
    const int* ei = br ? frag_ei : batch_ei;
    const int* ea = br ? frag_ea : batch_ea;

    // degree (by src, +1 self-loop) -> dinv
    hipMemsetAsync(degcnt, 0, (size_t)N*4, stream);
    k_count_src<<<CE(E,256),256,0,stream>>>(ei, E, degcnt);
    k_dinv<<<CE(N,256),256,0,stream>>>(degcnt, dinv, N);

    // dst-CSR over E real edges + N self-loops (layer-invariant)
    k_set_val<<<CE(N,256),256,0,stream>>>(counts, N, 1);
    k_count_dst<<<CE(E,256),256,0,stream>>>(ei, E, counts);
    scan_excl(counts, N, offs, bsum, stream);
    hipMemsetAsync(cursor, 0, (size_t)N*4, stream);
    k_fill_edges<<<CE(E+N,256),256,0,stream>>>(ei, ea, E, N, offs, cursor, entries);

    // h0 raw = ae1[x0] + ae2[x1]
    k_init_h0<<<N,256,0,stream>>>(x, ae1, ae2, hA, N);

    // 5 fused layers, ping-pong; BN affine+relu applied in the NEXT layer's gather
    for (int l = 0; l < 5; l++){
      const h16* src = (l & 1) ? hB : hA;
      h16*       dst = (l & 1) ? hA : hB;
      const h16* ch  = (l == 0) ? idcoefh : coefh;
      hipMemsetAsync(stats, 0, 2*EMBD*4, stream);
      if (l == 0)
        k_layer<0><<<LBLK,256,0,stream>>>(src, ch, dinv, offs, counts, entries,
                                          wext + (size_t)l*KEXT*KEXT, dst, N, stats);
      else
        k_layer<1><<<LBLK,256,0,stream>>>(src, ch, dinv, offs, counts, entries,
                                          wext + (size_t)l*KEXT*KEXT, dst, N, stats);
      k_bn_coef<<<CE(KEXT,256),256,0,stream>>>(stats, bn_gamma + l*EMBD, bn_beta + l*EMBD,
                                               coef, coefh, 1.0f/(float)N);
    }
    // hB holds raw layer-4 lin output; coef holds its BN affine (no relu on last layer):
    // BN commutes with mean-pool -> apply affine on pooled rows.

    if (br == 0){
      hipMemsetAsync(counts, 0, (size_t)NG*4, stream);
      k_count_ids<<<CE(N,256),256,0,stream>>>(batch_gid, N, counts);
      scan_excl(counts, NG, offs, bsum, stream);
      hipMemsetAsync(cursor, 0, (size_t)NG*4, stream);
      k_fill_rows<<<CE(N,256),256,0,stream>>>(batch_gid, N, offs, cursor, entries);
      k_pool_h<<<NG,256,0,stream>>>(hB, offs, counts, entries, g0, NG);
      k_affine_rows<<<NG,256,0,stream>>>(g0, coef, NG);
      gemm_f32(g0, LDF, jct_W, EMBD, jct_b,
               jct_ee1 + 4*EMBD, jct_ee2,
               t1, LDF, NG, EMBD, EMBD, 1, 1.0f, stream);
      gemm_f32(t1, LDF, jct_W + EMBD*EMBD, EMBD, jct_b + EMBD,
               jct_ee1 + 6*EMBD + 4*EMBD, jct_ee2 + 3*EMBD,
               f0, LDF, NG, EMBD, EMBD, 0, 1.0f, stream);
      k_l2norm<<<NG,256,0,stream>>>(f0, NG);
    } else {
      hipMemsetAsync(counts, 0, (size_t)NJ*4, stream);
      k_count_ids<<<CE(N,256),256,0,stream>>>(frag_jid, N, counts);
      scan_excl(counts, NJ, offs, bsum, stream);
      hipMemsetAsync(cursor, 0, (size_t)NJ*4, stream);
      k_fill_rows<<<CE(N,256),256,0,stream>>>(frag_jid, N, offs, cursor, entries);
      k_pool_h<<<NJ,256,0,stream>>>(hB, offs, counts, entries, t1, NJ);
      k_affine_rows<<<NJ,256,0,stream>>>(t1, coef, NJ);
      k_mask<<<NJ,256,0,stream>>>(t1, jct_mask, mask_emb, NJ);
      gemm_f32(t1, LDF, jct_W, EMBD, jct_b,
               jct_ee1 + 4*EMBD, jct_ee2,
               t2, LDF, NJ, EMBD, EMBD, 1, 1.0f, stream);
      gemm_f32(t2, LDF, jct_W + EMBD*EMBD, EMBD, jct_b + EMBD,
               jct_ee1 + 6*EMBD + 4*EMBD, jct_ee2 + 3*EMBD,
               t1, LDF, NJ, EMBD, EMBD, 0, 1.0f, stream);
      hipMemsetAsync(counts, 0, (size_t)NG*4, stream);
      k_count_ids<<<CE(NJ,256),256,0,stream>>>(jct_gid, NJ, counts);
      scan_excl(counts, NG, offs, bsum, stream);
      hipMemsetAsync(cursor, 0, (size_t)NG*4, stream);
      k_fill_rows<<<CE(NJ,256),256,0,stream>>>(jct_gid, NJ, offs, cursor, entries);
      k_pool_f32<<<NG,256,0,stream>>>(t1, offs, counts, entries, f1, NG);
      k_l2norm<<<NG,256,0,stream>>>(f1, NG);
    }
  }

  // logits = (f0 @ f1^T) / TEMP
  gemm_f32(f0, LDF, f1, LDF, nullptr, nullptr, nullptr,
           (float*)d_out, 1024, NG, NG, EMBD, 0, 25.0f, stream);
}